// Round 1
// baseline (2456.900 us; speedup 1.0000x reference)
//
#include <hip/hip_runtime.h>
#include <math.h>

#define NTOK 32768
#define DIM 256
#define KCB 8192
#define NCHUNK 8            // code chunks across blocks
#define CHUNK 1024          // codes per chunk
#define TT 128              // token tile per block
#define CT 128              // code sub-tile

// ---- numpy-pairwise ||row||^2 for a [rows][256] matrix -------------------
// Replicates np.sum(x*x, axis=1) bitwise: products rounded individually,
// pairwise blocks of 128 with 8 accumulators, combined ((r0+r1)+(r2+r3))+((r4+r5)+(r6+r7)).
__global__ __launch_bounds__(256)
void rownorm256_np(const float* __restrict__ M, float* __restrict__ out, int rows) {
  int r = blockIdx.x * 256 + threadIdx.x;
  if (r >= rows) return;
  const float* p = M + (size_t)r * DIM;
  float blk[2];
#pragma unroll
  for (int b = 0; b < 2; ++b) {
    const float* a = p + b * 128;
    float rr[8];
#pragma unroll
    for (int j = 0; j < 8; ++j) rr[j] = __fmul_rn(a[j], a[j]);
    for (int i = 8; i < 128; i += 8) {
#pragma unroll
      for (int j = 0; j < 8; ++j)
        rr[j] = __fadd_rn(rr[j], __fmul_rn(a[i + j], a[i + j]));
    }
    float s01 = __fadd_rn(rr[0], rr[1]);
    float s23 = __fadd_rn(rr[2], rr[3]);
    float s45 = __fadd_rn(rr[4], rr[5]);
    float s67 = __fadd_rn(rr[6], rr[7]);
    blk[b] = __fadd_rn(__fadd_rn(s01, s23), __fadd_rn(s45, s67));
  }
  out[r] = __fadd_rn(blk[0], blk[1]);
}

// ---- main: per (token-tile, code-chunk) block computes partial argmin ----
__global__ __launch_bounds__(256)
void vq_argmin_kernel(const float* __restrict__ z, const float* __restrict__ cb,
                      const float* __restrict__ An, const float* __restrict__ Cn,
                      float* __restrict__ pv, int* __restrict__ pk) {
  __shared__ float zs[64][TT];
  __shared__ float cs[64][CT];
  __shared__ float mv[TT][16];
  __shared__ int   mk[TT][16];

  const int tid = threadIdx.x;
  const int tx = tid & 15, ty = tid >> 4;
  const int chunk = blockIdx.x & 7;
  const int tile = blockIdx.x >> 3;
  const int base_t = tile * TT;
  const int base_k = chunk * CHUNK;

  float Areg[8];
#pragma unroll
  for (int i = 0; i < 8; ++i) Areg[i] = An[base_t + ty * 8 + i];

  float bestv[8]; int bestk[8];
#pragma unroll
  for (int i = 0; i < 8; ++i) { bestv[i] = INFINITY; bestk[i] = 0; }

  for (int st = 0; st < CHUNK / CT; ++st) {
    const int kb0 = base_k + st * CT;
    float acc[8][8];
#pragma unroll
    for (int i = 0; i < 8; ++i)
#pragma unroll
      for (int j = 0; j < 8; ++j) acc[i][j] = 0.f;

    for (int dc = 0; dc < DIM / 64; ++dc) {
      __syncthreads();
      // stage 64 d's x 128 rows of z and cb, transposed into LDS
#pragma unroll
      for (int li = tid; li < 64 * TT / 4; li += 256) {   // 2048 float4 per operand
        int row = li >> 4, dv = li & 15;
        float4 v = *reinterpret_cast<const float4*>(
            &z[(size_t)(base_t + row) * DIM + dc * 64 + dv * 4]);
        zs[dv * 4 + 0][row] = v.x; zs[dv * 4 + 1][row] = v.y;
        zs[dv * 4 + 2][row] = v.z; zs[dv * 4 + 3][row] = v.w;
        float4 c = *reinterpret_cast<const float4*>(
            &cb[(size_t)(kb0 + row) * DIM + dc * 64 + dv * 4]);
        cs[dv * 4 + 0][row] = c.x; cs[dv * 4 + 1][row] = c.y;
        cs[dv * 4 + 2][row] = c.z; cs[dv * 4 + 3][row] = c.w;
      }
      __syncthreads();
      // sequential-d fma accumulation (d ascending across dc) to mimic BLAS fma order
#pragma unroll 4
      for (int d = 0; d < 64; ++d) {
        const float4 za  = *reinterpret_cast<const float4*>(&zs[d][ty * 8]);
        const float4 zb  = *reinterpret_cast<const float4*>(&zs[d][ty * 8 + 4]);
        const float4 ca  = *reinterpret_cast<const float4*>(&cs[d][tx * 8]);
        const float4 cbv = *reinterpret_cast<const float4*>(&cs[d][tx * 8 + 4]);
        const float zv[8] = {za.x, za.y, za.z, za.w, zb.x, zb.y, zb.z, zb.w};
        const float cv[8] = {ca.x, ca.y, ca.z, ca.w, cbv.x, cbv.y, cbv.z, cbv.w};
#pragma unroll
        for (int i = 0; i < 8; ++i)
#pragma unroll
          for (int j = 0; j < 8; ++j)
            acc[i][j] = fmaf(zv[i], cv[j], acc[i][j]);
      }
    }
    // scores with ref's exact rounding chain: fl(fl(A - 2*dot) + C)
#pragma unroll
    for (int j = 0; j < 8; ++j) {
      const int klocal = st * CT + tx * 8 + j;
      const float Ck = Cn[base_k + klocal];
#pragma unroll
      for (int i = 0; i < 8; ++i) {
        float p2 = __fmul_rn(2.0f, acc[i][j]);   // exact (x2)
        float t1 = __fsub_rn(Areg[i], p2);       // one rounding
        float t  = __fadd_rn(t1, Ck);            // one rounding
        if (t < bestv[i]) { bestv[i] = t; bestk[i] = klocal; }  // first-min wins (k ascending)
      }
    }
  }

  __syncthreads();
#pragma unroll
  for (int i = 0; i < 8; ++i) { mv[ty * 8 + i][tx] = bestv[i]; mk[ty * 8 + i][tx] = bestk[i]; }
  __syncthreads();
  if (tid < TT) {
    float bv = mv[tid][0]; int bk = mk[tid][0];
#pragma unroll
    for (int x = 1; x < 16; ++x) {
      float v = mv[tid][x]; int k = mk[tid][x];
      if (v < bv || (v == bv && k < bk)) { bv = v; bk = k; }
    }
    size_t idx = (size_t)(base_t + tid) * NCHUNK + chunk;
    pv[idx] = bv;
    pk[idx] = base_k + bk;
  }
}

// ---- finalize: reduce chunks, gather z_q, ids, loss ----------------------
__global__ __launch_bounds__(256)
void vq_finalize(const float* __restrict__ z, const float* __restrict__ cb,
                 const float* __restrict__ pv, const int* __restrict__ pk,
                 float* __restrict__ out, double* __restrict__ loss_acc) {
  const int n = blockIdx.x * 4 + (threadIdx.x >> 6);
  const int lane = threadIdx.x & 63;
  float bv = INFINITY; int bk = 0;
#pragma unroll
  for (int c = 0; c < NCHUNK; ++c) {
    float v = pv[(size_t)n * NCHUNK + c];
    int k = pk[(size_t)n * NCHUNK + c];
    if (v < bv || (v == bv && k < bk)) { bv = v; bk = k; }
  }
  const float4 c4 = *reinterpret_cast<const float4*>(&cb[(size_t)bk * DIM + lane * 4]);
  const float4 z4 = *reinterpret_cast<const float4*>(&z[(size_t)n * DIM + lane * 4]);
  *reinterpret_cast<float4*>(&out[(size_t)n * DIM + lane * 4]) = c4;
  float dx = __fsub_rn(c4.x, z4.x), dy = __fsub_rn(c4.y, z4.y);
  float dz = __fsub_rn(c4.z, z4.z), dw = __fsub_rn(c4.w, z4.w);
  double s = (double)dx * dx + (double)dy * dy + (double)dz * dz + (double)dw * dw;
#pragma unroll
  for (int off = 32; off > 0; off >>= 1) s += __shfl_down(s, off);
  if (lane == 0) {
    out[(size_t)NTOK * DIM + n] = (float)bk;
    atomicAdd(loss_acc, s);
  }
}

__global__ void vq_loss_write(const double* __restrict__ loss_acc, float* __restrict__ out) {
  out[(size_t)NTOK * DIM + NTOK] = (float)(0.25 * (*loss_acc) / (double)((size_t)NTOK * DIM));
}

extern "C" void kernel_launch(void* const* d_in, const int* in_sizes, int n_in,
                              void* d_out, int out_size, void* d_ws, size_t ws_size,
                              hipStream_t stream) {
  const float* z  = (const float*)d_in[0];
  const float* cb = (const float*)d_in[1];
  float* out = (float*)d_out;
  char* ws = (char*)d_ws;
  // ws layout (bytes): A[32768]f @0, C[8192]f @131072, pv[32768*8]f @163840,
  // pk[32768*8]i @1212416, loss double @2260992  (total ~2.16 MB)
  float*  An = (float*)(ws);
  float*  Cn = (float*)(ws + 131072);
  float*  pv = (float*)(ws + 163840);
  int*    pk = (int*)(ws + 1212416);
  double* loss_acc = (double*)(ws + 2260992);

  hipMemsetAsync(loss_acc, 0, sizeof(double), stream);
  rownorm256_np<<<NTOK / 256, 256, 0, stream>>>(z, An, NTOK);
  rownorm256_np<<<KCB / 256, 256, 0, stream>>>(cb, Cn, KCB);
  vq_argmin_kernel<<<(NTOK / TT) * NCHUNK, 256, 0, stream>>>(z, cb, An, Cn, pv, pk);
  vq_finalize<<<NTOK / 4, 256, 0, stream>>>(z, cb, pv, pk, out, loss_acc);
  vq_loss_write<<<1, 1, 0, stream>>>(loss_acc, out);
}

// Round 3
// 2221.864 us; speedup vs baseline: 1.1058x; 1.1058x over previous
//
#include <hip/hip_runtime.h>
#include <math.h>

#define NTOK 32768
#define DIM 256
#define KCB 8192
#define NCHUNK 8            // code chunks across blocks
#define CHUNK 1024          // codes per chunk
#define TT 128              // token tile per block
#define CT 128              // code sub-tile
#define DC 32               // d-chunk staged in LDS per step

// ---- numpy-pairwise ||row||^2 for a [rows][256] matrix -------------------
// Replicates np.sum(x*x, axis=1) bitwise: products rounded individually,
// pairwise blocks of 128 with 8 accumulators, combined ((r0+r1)+(r2+r3))+((r4+r5)+(r6+r7)).
__global__ __launch_bounds__(256)
void rownorm256_np(const float* __restrict__ M, float* __restrict__ out, int rows) {
  int r = blockIdx.x * 256 + threadIdx.x;
  if (r >= rows) return;
  const float* p = M + (size_t)r * DIM;
  float blk[2];
#pragma unroll
  for (int b = 0; b < 2; ++b) {
    const float* a = p + b * 128;
    float rr[8];
#pragma unroll
    for (int j = 0; j < 8; ++j) rr[j] = __fmul_rn(a[j], a[j]);
    for (int i = 8; i < 128; i += 8) {
#pragma unroll
      for (int j = 0; j < 8; ++j)
        rr[j] = __fadd_rn(rr[j], __fmul_rn(a[i + j], a[i + j]));
    }
    float s01 = __fadd_rn(rr[0], rr[1]);
    float s23 = __fadd_rn(rr[2], rr[3]);
    float s45 = __fadd_rn(rr[4], rr[5]);
    float s67 = __fadd_rn(rr[6], rr[7]);
    blk[b] = __fadd_rn(__fadd_rn(s01, s23), __fadd_rn(s45, s67));
  }
  out[r] = __fadd_rn(blk[0], blk[1]);
}

// LDS swizzle: index(d, col) = d*128 + (col ^ ((d>>2)<<2) ^ ((col&32)>>3))
// Bits [1:0] untouched -> float4 granules stay contiguous. Stores spread to
// 2-way-or-better; fragment reads 2-way (free). BOTH operands and BOTH
// store/read sides must apply the full XOR (R2 bug: zs read missed bit5 term).

// ---- main: per (token-tile, code-chunk) block computes partial argmin ----
__global__ __launch_bounds__(256)
void vq_argmin_kernel(const float* __restrict__ z, const float* __restrict__ cb,
                      const float* __restrict__ An, const float* __restrict__ Cn,
                      float* __restrict__ pv, int* __restrict__ pk) {
  __shared__ float zs[DC * TT];     // 16 KB (aliased by mv/mk after main loop)
  __shared__ float cs[DC * CT];     // 16 KB

  const int tid = threadIdx.x;
  const int tx = tid & 15, ty = tid >> 4;
  const int chunk = blockIdx.x & 7;
  const int tile = blockIdx.x >> 3;
  const int base_t = tile * TT;
  const int base_k = chunk * CHUNK;

  float Areg[8];
#pragma unroll
  for (int i = 0; i < 8; ++i) Areg[i] = An[base_t + ty * 8 + i];

  float bestv[8]; int bestk[8];
#pragma unroll
  for (int i = 0; i < 8; ++i) { bestv[i] = INFINITY; bestk[i] = 0; }

  for (int st = 0; st < CHUNK / CT; ++st) {
    const int kb0 = base_k + st * CT;
    float acc[8][8];
#pragma unroll
    for (int i = 0; i < 8; ++i)
#pragma unroll
      for (int j = 0; j < 8; ++j) acc[i][j] = 0.f;

    for (int dc = 0; dc < DIM / DC; ++dc) {
      __syncthreads();
      // stage DC d's x 128 rows of z and cb, transposed + swizzled into LDS
#pragma unroll
      for (int li = tid; li < DC * TT / 4; li += 256) {   // 4 iters
        const int row = li >> 3;          // token/code row 0..127
        const int dv = li & 7;            // d-group (4 d's each)
        const int ibase = dv * 4 * 128 + (row ^ (dv << 2) ^ ((row & 32) >> 3));
        float4 v = *reinterpret_cast<const float4*>(
            &z[(size_t)(base_t + row) * DIM + dc * DC + dv * 4]);
        zs[ibase] = v.x; zs[ibase + 128] = v.y;
        zs[ibase + 256] = v.z; zs[ibase + 384] = v.w;
        float4 c = *reinterpret_cast<const float4*>(
            &cb[(size_t)(kb0 + row) * DIM + dc * DC + dv * 4]);
        cs[ibase] = c.x; cs[ibase + 128] = c.y;
        cs[ibase + 256] = c.z; cs[ibase + 384] = c.w;
      }
      __syncthreads();
      // sequential-d fma accumulation (d ascending globally) - chain identical to R1
#pragma unroll
      for (int dd = 0; dd < DC / 4; ++dd) {
        const int s1 = dd << 2;
        // full read swizzle: col ^ (dd<<2) ^ ((col&32)>>3); bit5-term = (ty&4)/(tx&4)
        const float* zp0 = &zs[dd * 4 * 128 + ((ty * 8) ^ s1 ^ (ty & 4))];
        const float* zp1 = &zs[dd * 4 * 128 + ((ty * 8 + 4) ^ s1 ^ (ty & 4))];
        const float* cp0 = &cs[dd * 4 * 128 + ((tx * 8) ^ s1 ^ (tx & 4))];
        const float* cp1 = &cs[dd * 4 * 128 + ((tx * 8 + 4) ^ s1 ^ (tx & 4))];
#pragma unroll
        for (int q = 0; q < 4; ++q) {
          const float4 za  = *reinterpret_cast<const float4*>(zp0 + q * 128);
          const float4 zb  = *reinterpret_cast<const float4*>(zp1 + q * 128);
          const float4 ca  = *reinterpret_cast<const float4*>(cp0 + q * 128);
          const float4 cbv = *reinterpret_cast<const float4*>(cp1 + q * 128);
          const float zv[8] = {za.x, za.y, za.z, za.w, zb.x, zb.y, zb.z, zb.w};
          const float cv[8] = {ca.x, ca.y, ca.z, ca.w, cbv.x, cbv.y, cbv.z, cbv.w};
#pragma unroll
          for (int i = 0; i < 8; ++i)
#pragma unroll
            for (int j = 0; j < 8; ++j)
              acc[i][j] = fmaf(zv[i], cv[j], acc[i][j]);
        }
      }
    }
    // scores with ref's exact rounding chain: fl(fl(A - 2*dot) + C)
#pragma unroll
    for (int j = 0; j < 8; ++j) {
      const int klocal = st * CT + tx * 8 + j;
      const float Ck = Cn[base_k + klocal];
#pragma unroll
      for (int i = 0; i < 8; ++i) {
        float p2 = __fmul_rn(2.0f, acc[i][j]);   // exact (x2)
        float t1 = __fsub_rn(Areg[i], p2);       // one rounding
        float t  = __fadd_rn(t1, Ck);            // one rounding
        if (t < bestv[i]) { bestv[i] = t; bestk[i] = klocal; }  // first-min wins (k ascending)
      }
    }
  }

  __syncthreads();
  // reduce 16 partial mins per token via LDS (aliased onto zs region)
  float (*mv)[16] = reinterpret_cast<float(*)[16]>(zs);          // 8 KB
  int   (*mk)[16] = reinterpret_cast<int(*)[16]>(zs + TT * 16);  // 8 KB
#pragma unroll
  for (int i = 0; i < 8; ++i) { mv[ty * 8 + i][tx] = bestv[i]; mk[ty * 8 + i][tx] = bestk[i]; }
  __syncthreads();
  if (tid < TT) {
    float bv = mv[tid][0]; int bk = mk[tid][0];
#pragma unroll
    for (int x = 1; x < 16; ++x) {
      float v = mv[tid][x]; int k = mk[tid][x];
      if (v < bv || (v == bv && k < bk)) { bv = v; bk = k; }
    }
    size_t idx = (size_t)(base_t + tid) * NCHUNK + chunk;
    pv[idx] = bv;
    pk[idx] = base_k + bk;
  }
}

// ---- finalize: reduce chunks, gather z_q, ids, loss ----------------------
__global__ __launch_bounds__(256)
void vq_finalize(const float* __restrict__ z, const float* __restrict__ cb,
                 const float* __restrict__ pv, const int* __restrict__ pk,
                 float* __restrict__ out, double* __restrict__ loss_acc) {
  const int n = blockIdx.x * 4 + (threadIdx.x >> 6);
  const int lane = threadIdx.x & 63;
  float bv = INFINITY; int bk = 0;
#pragma unroll
  for (int c = 0; c < NCHUNK; ++c) {
    float v = pv[(size_t)n * NCHUNK + c];
    int k = pk[(size_t)n * NCHUNK + c];
    if (v < bv || (v == bv && k < bk)) { bv = v; bk = k; }
  }
  const float4 c4 = *reinterpret_cast<const float4*>(&cb[(size_t)bk * DIM + lane * 4]);
  const float4 z4 = *reinterpret_cast<const float4*>(&z[(size_t)n * DIM + lane * 4]);
  *reinterpret_cast<float4*>(&out[(size_t)n * DIM + lane * 4]) = c4;
  float dx = __fsub_rn(c4.x, z4.x), dy = __fsub_rn(c4.y, z4.y);
  float dz = __fsub_rn(c4.z, z4.z), dw = __fsub_rn(c4.w, z4.w);
  double s = (double)dx * dx + (double)dy * dy + (double)dz * dz + (double)dw * dw;
#pragma unroll
  for (int off = 32; off > 0; off >>= 1) s += __shfl_down(s, off);
  if (lane == 0) {
    out[(size_t)NTOK * DIM + n] = (float)bk;
    atomicAdd(loss_acc, s);
  }
}

__global__ void vq_loss_write(const double* __restrict__ loss_acc, float* __restrict__ out) {
  out[(size_t)NTOK * DIM + NTOK] = (float)(0.25 * (*loss_acc) / (double)((size_t)NTOK * DIM));
}

extern "C" void kernel_launch(void* const* d_in, const int* in_sizes, int n_in,
                              void* d_out, int out_size, void* d_ws, size_t ws_size,
                              hipStream_t stream) {
  const float* z  = (const float*)d_in[0];
  const float* cb = (const float*)d_in[1];
  float* out = (float*)d_out;
  char* ws = (char*)d_ws;
  float*  An = (float*)(ws);
  float*  Cn = (float*)(ws + 131072);
  float*  pv = (float*)(ws + 163840);
  int*    pk = (int*)(ws + 1212416);
  double* loss_acc = (double*)(ws + 2260992);

  hipMemsetAsync(loss_acc, 0, sizeof(double), stream);
  rownorm256_np<<<NTOK / 256, 256, 0, stream>>>(z, An, NTOK);
  rownorm256_np<<<KCB / 256, 256, 0, stream>>>(cb, Cn, KCB);
  vq_argmin_kernel<<<(NTOK / TT) * NCHUNK, 256, 0, stream>>>(z, cb, An, Cn, pv, pk);
  vq_finalize<<<NTOK / 4, 256, 0, stream>>>(z, cb, pv, pk, out, loss_acc);
  vq_loss_write<<<1, 1, 0, stream>>>(loss_acc, out);
}

// Round 5
// 1411.381 us; speedup vs baseline: 1.7408x; 1.5742x over previous
//
#include <hip/hip_runtime.h>
#include <math.h>

#define NTOK 32768
#define DIM 256
#define KCB 8192
#define RESCUE_TAU 1e-3f
#define RPASS 8

typedef _Float16 half8 __attribute__((ext_vector_type(8)));
typedef float f32x4 __attribute__((ext_vector_type(4)));
typedef unsigned long long u64;

// ---------------- fast-path ws layout (bytes) ----------------
#define OFF_AN    0ull
#define OFF_CN    131072ull
#define OFF_IDS   163840ull
#define OFF_RCNT  294912ull
#define OFF_RLIST 295040ull
#define OFF_LOSS  426112ull
#define OFF_PK1   426240ull      // u64 [32768][8]
#define OFF_PV2   2523392ull     // f32 [32768][8]
#define OFF_Z16   3571968ull     // [256 tile][8 ks][128 row][64 halves swz]
#define OFF_CB16  37126400ull    // [32 tile][8 ks][256 row][64 halves swz]
#define WS_NEED   45515008ull

#define GLOAD_LDS16(gp, lp) __builtin_amdgcn_global_load_lds( \
    (const __attribute__((address_space(1))) void*)(gp), \
    (__attribute__((address_space(3))) void*)(lp), 16, 0, 0)

// ---- numpy-pairwise ||row||^2 (bitwise-matching np.sum(x*x,axis=1)) ------
__global__ __launch_bounds__(256)
void rownorm256_np(const float* __restrict__ M, float* __restrict__ out, int rows) {
  int r = blockIdx.x * 256 + threadIdx.x;
  if (r >= rows) return;
  const float* p = M + (size_t)r * DIM;
  float blk[2];
#pragma unroll
  for (int b = 0; b < 2; ++b) {
    const float* a = p + b * 128;
    float rr[8];
#pragma unroll
    for (int j = 0; j < 8; ++j) rr[j] = __fmul_rn(a[j], a[j]);
    for (int i = 8; i < 128; i += 8) {
#pragma unroll
      for (int j = 0; j < 8; ++j)
        rr[j] = __fadd_rn(rr[j], __fmul_rn(a[i + j], a[i + j]));
    }
    float s01 = __fadd_rn(rr[0], rr[1]);
    float s23 = __fadd_rn(rr[2], rr[3]);
    float s45 = __fadd_rn(rr[4], rr[5]);
    float s67 = __fadd_rn(rr[6], rr[7]);
    blk[b] = __fadd_rn(__fadd_rn(s01, s23), __fadd_rn(s45, s67));
  }
  out[r] = __fadd_rn(blk[0], blk[1]);
}

// ---- convert: fp32 -> scaled fp16 (hi,lo) pair, pre-swizzled tiled layout ----
__global__ __launch_bounds__(128)
void conv_z16(const float* __restrict__ z, _Float16* __restrict__ dst) {
  const int tile = blockIdx.x >> 3, ks = blockIdx.x & 7, row = threadIdx.x;
  const float* src = z + ((size_t)(tile * 128 + row)) * DIM + ks * 32;
  _Float16* d = dst + (u64)tile * 65536 + (u64)ks * 8192 + row * 64;
  const int rs = row & 7;
#pragma unroll
  for (int q = 0; q < 4; ++q) {
    half8 hv, lv;
#pragma unroll
    for (int j = 0; j < 8; ++j) {
      float f = src[q * 8 + j] * 64.0f;          // exact pow2 scale
      _Float16 h = (_Float16)f;                  // RNE
      float lf = f - (float)h;                   // exact
      hv[j] = h; lv[j] = (_Float16)lf;
    }
    *reinterpret_cast<half8*>(d + ((q ^ rs) * 8)) = hv;
    *reinterpret_cast<half8*>(d + (((q + 4) ^ rs) * 8)) = lv;
  }
}

__global__ __launch_bounds__(256)
void conv_cb16(const float* __restrict__ cb, _Float16* __restrict__ dst) {
  const int tile = blockIdx.x >> 3, ks = blockIdx.x & 7, row = threadIdx.x;
  const float* src = cb + ((size_t)(tile * 256 + row)) * DIM + ks * 32;
  _Float16* d = dst + (u64)tile * 131072 + (u64)ks * 16384 + row * 64;
  const int rs = row & 7;
#pragma unroll
  for (int q = 0; q < 4; ++q) {
    half8 hv, lv;
#pragma unroll
    for (int j = 0; j < 8; ++j) {
      float f = src[q * 8 + j] * 1024.0f;        // exact pow2 scale
      _Float16 h = (_Float16)f;
      float lf = f - (float)h;
      hv[j] = h; lv[j] = (_Float16)lf;
    }
    *reinterpret_cast<half8*>(d + ((q ^ rs) * 8)) = hv;
    *reinterpret_cast<half8*>(d + (((q + 4) ^ rs) * 8)) = lv;
  }
}

// ---- MFMA GEMM + per-cgroup top-2 ----------------------------------------
// Block: 128 tokens x 1024 codes (4 sub-tiles of 256), 4 waves (2m x 2n).
// Writes per-(token, cgroup) (best u64 key, second-best distance).
__global__ __launch_bounds__(256, 3)
void vq_mfma_top2(const _Float16* __restrict__ z16, const _Float16* __restrict__ cb16,
                  const float* __restrict__ An, const float* __restrict__ Cn,
                  u64* __restrict__ pk1, float* __restrict__ pv2) {
  __shared__ _Float16 As[128 * 64];   // 16 KB
  __shared__ _Float16 Bs[256 * 64];   // 32 KB
  __shared__ u64 t2[128][2][2];       // [tloc][wn][{k1,k2}]  4 KB

  const int tid = threadIdx.x;
  const int lane = tid & 63, w = tid >> 6;
  const int wm = w >> 1, wn = w & 1;
  const int ttile = blockIdx.x >> 3, cg = blockIdx.x & 7;
  const int laneM = lane & 15, laneK = lane >> 4;
  const u64 zbase = (u64)ttile * 65536;

  if (tid < 256) {  // init top-2 slots (one entry per thread: 128*2 = 256)
    t2[tid >> 1][tid & 1][0] = ~0ull;
    t2[tid >> 1][tid & 1][1] = ~0ull;
  }

  int offAh[4], offAl[4], offBh[8], offBl[8];
#pragma unroll
  for (int f = 0; f < 4; ++f) {
    int row = wm * 64 + f * 16 + laneM;
    offAh[f] = row * 64 + ((laneK ^ (row & 7)) * 8);
    offAl[f] = row * 64 + (((laneK + 4) ^ (row & 7)) * 8);
  }
#pragma unroll
  for (int g = 0; g < 8; ++g) {
    int row = wn * 128 + g * 16 + laneM;
    offBh[g] = row * 64 + ((laneK ^ (row & 7)) * 8);
    offBl[g] = row * 64 + (((laneK + 4) ^ (row & 7)) * 8);
  }

  for (int sub = 0; sub < 4; ++sub) {
    const int ctile = cg * 4 + sub;
    const u64 cbase = (u64)ctile * 131072;

    f32x4 acc[4][8];
#pragma unroll
    for (int f = 0; f < 4; ++f)
#pragma unroll
      for (int g = 0; g < 8; ++g) acc[f][g] = (f32x4){0.f, 0.f, 0.f, 0.f};

    for (int ks = 0; ks < 8; ++ks) {
      __syncthreads();   // previous tile's reads / epilogue complete
      {
        const _Float16* zs = z16 + zbase + (u64)ks * 8192 + tid * 8;
        const _Float16* bs = cb16 + cbase + (u64)ks * 16384 + tid * 8;
#pragma unroll
        for (int t = 0; t < 4; ++t) GLOAD_LDS16(zs + t * 2048, &As[(tid + t * 256) * 8]);
#pragma unroll
        for (int t = 0; t < 8; ++t) GLOAD_LDS16(bs + t * 2048, &Bs[(tid + t * 256) * 8]);
      }
      __syncthreads();   // staging complete

      half8 ah[4], al[4];
#pragma unroll
      for (int f = 0; f < 4; ++f) {
        ah[f] = *reinterpret_cast<const half8*>(&As[offAh[f]]);
        al[f] = *reinterpret_cast<const half8*>(&As[offAl[f]]);
      }
#pragma unroll
      for (int h = 0; h < 2; ++h) {
        half8 bh[4], bl[4];
#pragma unroll
        for (int g = 0; g < 4; ++g) {
          bh[g] = *reinterpret_cast<const half8*>(&Bs[offBh[h * 4 + g]]);
          bl[g] = *reinterpret_cast<const half8*>(&Bs[offBl[h * 4 + g]]);
        }
#pragma unroll
        for (int f = 0; f < 4; ++f)
#pragma unroll
          for (int g = 0; g < 4; ++g)
            acc[f][h * 4 + g] = __builtin_amdgcn_mfma_f32_16x16x32_f16(ah[f], bh[g], acc[f][h * 4 + g], 0, 0, 0);
#pragma unroll
        for (int f = 0; f < 4; ++f)
#pragma unroll
          for (int g = 0; g < 4; ++g)
            acc[f][h * 4 + g] = __builtin_amdgcn_mfma_f32_16x16x32_f16(al[f], bh[g], acc[f][h * 4 + g], 0, 0, 0);
#pragma unroll
        for (int f = 0; f < 4; ++f)
#pragma unroll
          for (int g = 0; g < 4; ++g)
            acc[f][h * 4 + g] = __builtin_amdgcn_mfma_f32_16x16x32_f16(ah[f], bl[g], acc[f][h * 4 + g], 0, 0, 0);
      }
    }

    // epilogue: exact score chain + per-lane top-2 + lane-merge + LDS merge
    float Creg[8];
#pragma unroll
    for (int g = 0; g < 8; ++g) Creg[g] = Cn[ctile * 256 + wn * 128 + g * 16 + laneM];
#pragma unroll
    for (int f = 0; f < 4; ++f) {
#pragma unroll
      for (int r = 0; r < 4; ++r) {
        const int tloc = wm * 64 + f * 16 + laneK * 4 + r;
        const float Ar = An[ttile * 128 + tloc];
        u64 k1 = ~0ull, k2 = ~0ull;
#pragma unroll
        for (int g = 0; g < 8; ++g) {
          float p2 = __fmul_rn(acc[f][g][r], 0x1p-15f);   // 2*dot, exact pow2
          float t1 = __fsub_rn(Ar, p2);
          float t  = __fadd_rn(t1, Creg[g]);
          u64 key = ((u64)__float_as_uint(t) << 32) |
                    (u64)(ctile * 256 + wn * 128 + g * 16 + laneM);
          if (key < k1) { k2 = k1; k1 = key; }
          else if (key < k2) { k2 = key; }
        }
#pragma unroll
        for (int d = 8; d > 0; d >>= 1) {
          u64 o1 = __shfl_xor(k1, d);
          u64 o2 = __shfl_xor(k2, d);
          u64 n1 = (k1 < o1) ? k1 : o1;
          u64 hi = (k1 < o1) ? o1 : k1;
          u64 l2 = (k2 < o2) ? k2 : o2;
          k1 = n1; k2 = (hi < l2) ? hi : l2;
        }
        if (laneM == 0) {
          u64 s1 = t2[tloc][wn][0], s2 = t2[tloc][wn][1];
          u64 n1 = (s1 < k1) ? s1 : k1;
          u64 hi = (s1 < k1) ? k1 : s1;
          u64 l2 = (s2 < k2) ? s2 : k2;
          t2[tloc][wn][0] = n1;
          t2[tloc][wn][1] = (hi < l2) ? hi : l2;
        }
      }
    }
  }

  __syncthreads();
  if (tid < 128) {
    u64 a1 = t2[tid][0][0], a2 = t2[tid][0][1];
    u64 b1 = t2[tid][1][0], b2 = t2[tid][1][1];
    u64 K1 = (a1 < b1) ? a1 : b1;
    u64 hi = (a1 < b1) ? b1 : a1;
    u64 l2 = (a2 < b2) ? a2 : b2;
    u64 K2 = (hi < l2) ? hi : l2;
    const int token = ttile * 128 + tid;
    pk1[(size_t)token * 8 + cg] = K1;
    pv2[(size_t)token * 8 + cg] = __uint_as_float((unsigned)(K2 >> 32));
  }
}

// ---- detect: merge 8 cgroup top-2, write candidate ids, flag near-ties ----
__global__ __launch_bounds__(256)
void vq_detect(const u64* __restrict__ pk1, const float* __restrict__ pv2,
               int* __restrict__ ids, int* __restrict__ rcnt, int* __restrict__ rlist) {
  const int token = blockIdx.x * 256 + threadIdx.x;
  u64 K1 = pk1[(size_t)token * 8];
  float V2 = pv2[(size_t)token * 8];
#pragma unroll
  for (int c = 1; c < 8; ++c) {
    u64 k1 = pk1[(size_t)token * 8 + c];
    float v2 = pv2[(size_t)token * 8 + c];
    u64 n1 = (k1 < K1) ? k1 : K1;
    u64 hi = (k1 < K1) ? K1 : k1;
    float loser = __uint_as_float((unsigned)(hi >> 32));
    V2 = fminf(fminf(V2, v2), loser);
    K1 = n1;
  }
  ids[token] = (int)(K1 & 0xffffffffull);
  float d1 = __uint_as_float((unsigned)(K1 >> 32));
  if (V2 - d1 < RESCUE_TAU) {
    int p = atomicAdd(rcnt, 1);
    rlist[p] = token;
  }
}

// ---- rescue: exact R3-chain rescan of flagged tokens over all codes ------
__global__ __launch_bounds__(256)
void vq_rescue(const float* __restrict__ z, const float* __restrict__ cb,
               const float* __restrict__ An, const float* __restrict__ Cn,
               const int* __restrict__ rcnt, const int* __restrict__ rlist,
               int* __restrict__ ids) {
  __shared__ float zrow[RPASS][256];
  __shared__ u64 red[256];
  const int tid = threadIdx.x;
  const int total = *rcnt;
  for (int base = blockIdx.x * RPASS; base < total; base += gridDim.x * RPASS) {
    const int np = min(RPASS, total - base);
    __syncthreads();
    for (int li = tid; li < np * 256; li += 256)
      zrow[li >> 8][li & 255] = z[(size_t)rlist[base + (li >> 8)] * DIM + (li & 255)];
    __syncthreads();
    float Atok[RPASS];
#pragma unroll
    for (int s = 0; s < RPASS; ++s) Atok[s] = (s < np) ? An[rlist[base + s]] : 0.f;
    u64 bkey[RPASS];
#pragma unroll
    for (int s = 0; s < RPASS; ++s) bkey[s] = ~0ull;
    for (int jj = 0; jj < KCB / 256; ++jj) {
      const int j = jj * 256 + tid;
      const float4* crow = reinterpret_cast<const float4*>(cb + (size_t)j * DIM);
      float dots[RPASS];
#pragma unroll
      for (int s = 0; s < RPASS; ++s) dots[s] = 0.f;
      for (int k4 = 0; k4 < 64; ++k4) {
        const float4 c4 = crow[k4];
#pragma unroll
        for (int s = 0; s < RPASS; ++s) {   // k ascending, same fmaf chain as R3
          const float4 z4 = *reinterpret_cast<const float4*>(&zrow[s][k4 * 4]);
          dots[s] = fmaf(z4.x, c4.x, dots[s]);
          dots[s] = fmaf(z4.y, c4.y, dots[s]);
          dots[s] = fmaf(z4.z, c4.z, dots[s]);
          dots[s] = fmaf(z4.w, c4.w, dots[s]);
        }
      }
      const float Cj = Cn[j];
#pragma unroll
      for (int s = 0; s < RPASS; ++s) {
        float p2 = __fmul_rn(2.0f, dots[s]);
        float t1 = __fsub_rn(Atok[s], p2);
        float t  = __fadd_rn(t1, Cj);
        u64 key = ((u64)__float_as_uint(t) << 32) | (u64)j;
        if (key < bkey[s]) bkey[s] = key;
      }
    }
    for (int s = 0; s < np; ++s) {
      __syncthreads();
      red[tid] = bkey[s];
      __syncthreads();
      for (int off = 128; off > 0; off >>= 1) {
        if (tid < off) { u64 o = red[tid + off]; if (o < red[tid]) red[tid] = o; }
        __syncthreads();
      }
      if (tid == 0) ids[rlist[base + s]] = (int)(red[0] & 0xffffffffull);
    }
  }
}

// ---- finalize: gather z_q, ids, loss -------------------------------------
__global__ __launch_bounds__(256)
void vq_finalize_ids(const float* __restrict__ z, const float* __restrict__ cb,
                     const int* __restrict__ ids, float* __restrict__ out,
                     double* __restrict__ loss_acc) {
  const int n = blockIdx.x * 4 + (threadIdx.x >> 6);
  const int lane = threadIdx.x & 63;
  const int bk = ids[n];
  const float4 c4 = *reinterpret_cast<const float4*>(&cb[(size_t)bk * DIM + lane * 4]);
  const float4 z4 = *reinterpret_cast<const float4*>(&z[(size_t)n * DIM + lane * 4]);
  *reinterpret_cast<float4*>(&out[(size_t)n * DIM + lane * 4]) = c4;
  float dx = __fsub_rn(c4.x, z4.x), dy = __fsub_rn(c4.y, z4.y);
  float dz = __fsub_rn(c4.z, z4.z), dw = __fsub_rn(c4.w, z4.w);
  double s = (double)dx * dx + (double)dy * dy + (double)dz * dz + (double)dw * dw;
#pragma unroll
  for (int off = 32; off > 0; off >>= 1) s += __shfl_down(s, off);
  if (lane == 0) {
    out[(size_t)NTOK * DIM + n] = (float)bk;
    atomicAdd(loss_acc, s);
  }
}

__global__ void vq_loss_write(const double* __restrict__ loss_acc, float* __restrict__ out) {
  out[(size_t)NTOK * DIM + NTOK] = (float)(0.25 * (*loss_acc) / (double)((size_t)NTOK * DIM));
}

// ======================= R3 fallback path (ws too small) ==================
#define NCHUNK 8
#define CHUNK 1024
#define TT 128
#define CT 128
#define DC 32

__global__ __launch_bounds__(256)
void vq_argmin_kernel(const float* __restrict__ z, const float* __restrict__ cb,
                      const float* __restrict__ An, const float* __restrict__ Cn,
                      float* __restrict__ pv, int* __restrict__ pk) {
  __shared__ float zs[DC * TT];
  __shared__ float cs[DC * CT];
  const int tid = threadIdx.x;
  const int tx = tid & 15, ty = tid >> 4;
  const int chunk = blockIdx.x & 7;
  const int tile = blockIdx.x >> 3;
  const int base_t = tile * TT;
  const int base_k = chunk * CHUNK;
  float Areg[8];
#pragma unroll
  for (int i = 0; i < 8; ++i) Areg[i] = An[base_t + ty * 8 + i];
  float bestv[8]; int bestk[8];
#pragma unroll
  for (int i = 0; i < 8; ++i) { bestv[i] = INFINITY; bestk[i] = 0; }
  for (int st = 0; st < CHUNK / CT; ++st) {
    const int kb0 = base_k + st * CT;
    float acc[8][8];
#pragma unroll
    for (int i = 0; i < 8; ++i)
#pragma unroll
      for (int j = 0; j < 8; ++j) acc[i][j] = 0.f;
    for (int dc = 0; dc < DIM / DC; ++dc) {
      __syncthreads();
#pragma unroll
      for (int li = tid; li < DC * TT / 4; li += 256) {
        const int row = li >> 3;
        const int dv = li & 7;
        const int ibase = dv * 4 * 128 + (row ^ (dv << 2) ^ ((row & 32) >> 3));
        float4 v = *reinterpret_cast<const float4*>(
            &z[(size_t)(base_t + row) * DIM + dc * DC + dv * 4]);
        zs[ibase] = v.x; zs[ibase + 128] = v.y;
        zs[ibase + 256] = v.z; zs[ibase + 384] = v.w;
        float4 c = *reinterpret_cast<const float4*>(
            &cb[(size_t)(kb0 + row) * DIM + dc * DC + dv * 4]);
        cs[ibase] = c.x; cs[ibase + 128] = c.y;
        cs[ibase + 256] = c.z; cs[ibase + 384] = c.w;
      }
      __syncthreads();
#pragma unroll
      for (int dd = 0; dd < DC / 4; ++dd) {
        const int s1 = dd << 2;
        const float* zp0 = &zs[dd * 4 * 128 + ((ty * 8) ^ s1 ^ (ty & 4))];
        const float* zp1 = &zs[dd * 4 * 128 + ((ty * 8 + 4) ^ s1 ^ (ty & 4))];
        const float* cp0 = &cs[dd * 4 * 128 + ((tx * 8) ^ s1 ^ (tx & 4))];
        const float* cp1 = &cs[dd * 4 * 128 + ((tx * 8 + 4) ^ s1 ^ (tx & 4))];
#pragma unroll
        for (int q = 0; q < 4; ++q) {
          const float4 za  = *reinterpret_cast<const float4*>(zp0 + q * 128);
          const float4 zb  = *reinterpret_cast<const float4*>(zp1 + q * 128);
          const float4 ca  = *reinterpret_cast<const float4*>(cp0 + q * 128);
          const float4 cbv = *reinterpret_cast<const float4*>(cp1 + q * 128);
          const float zv[8] = {za.x, za.y, za.z, za.w, zb.x, zb.y, zb.z, zb.w};
          const float cv[8] = {ca.x, ca.y, ca.z, ca.w, cbv.x, cbv.y, cbv.z, cbv.w};
#pragma unroll
          for (int i = 0; i < 8; ++i)
#pragma unroll
            for (int j = 0; j < 8; ++j)
              acc[i][j] = fmaf(zv[i], cv[j], acc[i][j]);
        }
      }
    }
#pragma unroll
    for (int j = 0; j < 8; ++j) {
      const int klocal = st * CT + tx * 8 + j;
      const float Ck = Cn[base_k + klocal];
#pragma unroll
      for (int i = 0; i < 8; ++i) {
        float p2 = __fmul_rn(2.0f, acc[i][j]);
        float t1 = __fsub_rn(Areg[i], p2);
        float t  = __fadd_rn(t1, Ck);
        if (t < bestv[i]) { bestv[i] = t; bestk[i] = klocal; }
      }
    }
  }
  __syncthreads();
  float (*mv)[16] = reinterpret_cast<float(*)[16]>(zs);
  int   (*mk)[16] = reinterpret_cast<int(*)[16]>(zs + TT * 16);
#pragma unroll
  for (int i = 0; i < 8; ++i) { mv[ty * 8 + i][tx] = bestv[i]; mk[ty * 8 + i][tx] = bestk[i]; }
  __syncthreads();
  if (tid < TT) {
    float bv = mv[tid][0]; int bk = mk[tid][0];
#pragma unroll
    for (int x = 1; x < 16; ++x) {
      float v = mv[tid][x]; int k = mk[tid][x];
      if (v < bv || (v == bv && k < bk)) { bv = v; bk = k; }
    }
    size_t idx = (size_t)(base_t + tid) * NCHUNK + chunk;
    pv[idx] = bv;
    pk[idx] = base_k + bk;
  }
}

__global__ __launch_bounds__(256)
void vq_finalize(const float* __restrict__ z, const float* __restrict__ cb,
                 const float* __restrict__ pv, const int* __restrict__ pk,
                 float* __restrict__ out, double* __restrict__ loss_acc) {
  const int n = blockIdx.x * 4 + (threadIdx.x >> 6);
  const int lane = threadIdx.x & 63;
  float bv = INFINITY; int bk = 0;
#pragma unroll
  for (int c = 0; c < NCHUNK; ++c) {
    float v = pv[(size_t)n * NCHUNK + c];
    int k = pk[(size_t)n * NCHUNK + c];
    if (v < bv || (v == bv && k < bk)) { bv = v; bk = k; }
  }
  const float4 c4 = *reinterpret_cast<const float4*>(&cb[(size_t)bk * DIM + lane * 4]);
  const float4 z4 = *reinterpret_cast<const float4*>(&z[(size_t)n * DIM + lane * 4]);
  *reinterpret_cast<float4*>(&out[(size_t)n * DIM + lane * 4]) = c4;
  float dx = __fsub_rn(c4.x, z4.x), dy = __fsub_rn(c4.y, z4.y);
  float dz = __fsub_rn(c4.z, z4.z), dw = __fsub_rn(c4.w, z4.w);
  double s = (double)dx * dx + (double)dy * dy + (double)dz * dz + (double)dw * dw;
#pragma unroll
  for (int off = 32; off > 0; off >>= 1) s += __shfl_down(s, off);
  if (lane == 0) {
    out[(size_t)NTOK * DIM + n] = (float)bk;
    atomicAdd(loss_acc, s);
  }
}

// ==========================================================================
extern "C" void kernel_launch(void* const* d_in, const int* in_sizes, int n_in,
                              void* d_out, int out_size, void* d_ws, size_t ws_size,
                              hipStream_t stream) {
  const float* z  = (const float*)d_in[0];
  const float* cb = (const float*)d_in[1];
  float* out = (float*)d_out;
  char* ws = (char*)d_ws;

  if (ws_size >= WS_NEED) {
    float*     An   = (float*)(ws + OFF_AN);
    float*     Cn   = (float*)(ws + OFF_CN);
    int*       ids  = (int*)(ws + OFF_IDS);
    int*       rcnt = (int*)(ws + OFF_RCNT);
    int*       rlist= (int*)(ws + OFF_RLIST);
    double*    loss = (double*)(ws + OFF_LOSS);
    u64*       pk1  = (u64*)(ws + OFF_PK1);
    float*     pv2  = (float*)(ws + OFF_PV2);
    _Float16*  z16  = (_Float16*)(ws + OFF_Z16);
    _Float16*  c16  = (_Float16*)(ws + OFF_CB16);

    hipMemsetAsync(rcnt, 0, 128, stream);
    hipMemsetAsync(loss, 0, sizeof(double), stream);
    rownorm256_np<<<NTOK / 256, 256, 0, stream>>>(z, An, NTOK);
    rownorm256_np<<<KCB / 256, 256, 0, stream>>>(cb, Cn, KCB);
    conv_z16<<<256 * 8, 128, 0, stream>>>(z, z16);
    conv_cb16<<<32 * 8, 256, 0, stream>>>(cb, c16);
    vq_mfma_top2<<<256 * 8, 256, 0, stream>>>(z16, c16, An, Cn, pk1, pv2);
    vq_detect<<<NTOK / 256, 256, 0, stream>>>(pk1, pv2, ids, rcnt, rlist);
    vq_rescue<<<64, 256, 0, stream>>>(z, cb, An, Cn, rcnt, rlist, ids);
    vq_finalize_ids<<<NTOK / 4, 256, 0, stream>>>(z, cb, ids, out, loss);
    vq_loss_write<<<1, 1, 0, stream>>>(loss, out);
  } else {
    // R3 fallback (needs ~2.26 MB)
    float*  An = (float*)(ws);
    float*  Cn = (float*)(ws + 131072);
    float*  pv = (float*)(ws + 163840);
    int*    pk = (int*)(ws + 1212416);
    double* loss = (double*)(ws + 2260992);
    hipMemsetAsync(loss, 0, sizeof(double), stream);
    rownorm256_np<<<NTOK / 256, 256, 0, stream>>>(z, An, NTOK);
    rownorm256_np<<<KCB / 256, 256, 0, stream>>>(cb, Cn, KCB);
    vq_argmin_kernel<<<(NTOK / TT) * NCHUNK, 256, 0, stream>>>(z, cb, An, Cn, pv, pk);
    vq_finalize<<<NTOK / 4, 256, 0, stream>>>(z, cb, pv, pk, out, loss);
    vq_loss_write<<<1, 1, 0, stream>>>(loss, out);
  }
}

// Round 7
// 974.263 us; speedup vs baseline: 2.5218x; 1.4487x over previous
//
#include <hip/hip_runtime.h>
#include <math.h>

#define NTOK 32768
#define DIM 256
#define KCB 8192
#define RESCUE_TAU 1e-3f
#define RPASS 8

typedef _Float16 half8 __attribute__((ext_vector_type(8)));
typedef float f32x4 __attribute__((ext_vector_type(4)));
typedef unsigned long long u64;

// ---------------- fast-path ws layout (bytes) ----------------
#define OFF_AN    0ull
#define OFF_CN    131072ull
#define OFF_IDS   163840ull
#define OFF_RCNT  294912ull
#define OFF_RLIST 295040ull
#define OFF_PART  426112ull      // 2048 doubles
#define OFF_PK1   442496ull      // u64 [32768][8]
#define OFF_PV2   2539648ull     // f32 [32768][8]
#define OFF_Z16   3588224ull     // [256 tile][8 ks][128 row][64 halves swz]
#define OFF_CB16  37142656ull    // [32 tile][8 ks][256 row][64 halves swz]
#define WS_NEED   45531264ull

#define GLOAD_LDS16(gp, lp) __builtin_amdgcn_global_load_lds( \
    (const __attribute__((address_space(1))) void*)(gp), \
    (__attribute__((address_space(3))) void*)(lp), 16, 0, 0)

// ---- numpy-pairwise ||row||^2 (bitwise-matching np.sum(x*x,axis=1)) ------
__global__ __launch_bounds__(256)
void rownorm256_np(const float* __restrict__ M, float* __restrict__ out, int rows) {
  int r = blockIdx.x * 256 + threadIdx.x;
  if (r >= rows) return;
  const float* p = M + (size_t)r * DIM;
  float blk[2];
#pragma unroll
  for (int b = 0; b < 2; ++b) {
    const float* a = p + b * 128;
    float rr[8];
#pragma unroll
    for (int j = 0; j < 8; ++j) rr[j] = __fmul_rn(a[j], a[j]);
    for (int i = 8; i < 128; i += 8) {
#pragma unroll
      for (int j = 0; j < 8; ++j)
        rr[j] = __fadd_rn(rr[j], __fmul_rn(a[i + j], a[i + j]));
    }
    float s01 = __fadd_rn(rr[0], rr[1]);
    float s23 = __fadd_rn(rr[2], rr[3]);
    float s45 = __fadd_rn(rr[4], rr[5]);
    float s67 = __fadd_rn(rr[6], rr[7]);
    blk[b] = __fadd_rn(__fadd_rn(s01, s23), __fadd_rn(s45, s67));
  }
  out[r] = __fadd_rn(blk[0], blk[1]);
}

// ---- convert: fp32 -> scaled fp16 (hi,lo) pair, pre-swizzled tiled layout ----
__global__ __launch_bounds__(128)
void conv_z16(const float* __restrict__ z, _Float16* __restrict__ dst) {
  const int tile = blockIdx.x >> 3, ks = blockIdx.x & 7, row = threadIdx.x;
  const float* src = z + ((size_t)(tile * 128 + row)) * DIM + ks * 32;
  _Float16* d = dst + (u64)tile * 65536 + (u64)ks * 8192 + row * 64;
  const int rs = row & 7;
#pragma unroll
  for (int q = 0; q < 4; ++q) {
    half8 hv, lv;
#pragma unroll
    for (int j = 0; j < 8; ++j) {
      float f = src[q * 8 + j] * 64.0f;          // exact pow2 scale
      _Float16 h = (_Float16)f;                  // RNE
      float lf = f - (float)h;                   // exact
      hv[j] = h; lv[j] = (_Float16)lf;
    }
    *reinterpret_cast<half8*>(d + ((q ^ rs) * 8)) = hv;
    *reinterpret_cast<half8*>(d + (((q + 4) ^ rs) * 8)) = lv;
  }
}

__global__ __launch_bounds__(256)
void conv_cb16(const float* __restrict__ cb, _Float16* __restrict__ dst) {
  const int tile = blockIdx.x >> 3, ks = blockIdx.x & 7, row = threadIdx.x;
  const float* src = cb + ((size_t)(tile * 256 + row)) * DIM + ks * 32;
  _Float16* d = dst + (u64)tile * 131072 + (u64)ks * 16384 + row * 64;
  const int rs = row & 7;
#pragma unroll
  for (int q = 0; q < 4; ++q) {
    half8 hv, lv;
#pragma unroll
    for (int j = 0; j < 8; ++j) {
      float f = src[q * 8 + j] * 1024.0f;        // exact pow2 scale
      _Float16 h = (_Float16)f;
      float lf = f - (float)h;
      hv[j] = h; lv[j] = (_Float16)lf;
    }
    *reinterpret_cast<half8*>(d + ((q ^ rs) * 8)) = hv;
    *reinterpret_cast<half8*>(d + (((q + 4) ^ rs) * 8)) = lv;
  }
}

// ---- MFMA GEMM + per-cgroup top-2, 2-phase double-buffered ---------------
// Block: 128 tokens x 128 codes, 4 waves (2m x 2n), wave-tile 64x64.
// 64 steps = 8 subs (128-code col tiles of this cg's 1024) x 8 ks (K=32).
// Stage next step's tiles BEFORE current compute; the implicit vmcnt(0)
// drain of each __syncthreads publishes the prefetched buffer.
__global__ __launch_bounds__(256, 2)
void vq_mfma_top2(const _Float16* __restrict__ z16, const _Float16* __restrict__ cb16,
                  const float* __restrict__ An, const float* __restrict__ Cn,
                  u64* __restrict__ pk1, float* __restrict__ pv2) {
  __shared__ _Float16 As[2][128 * 64];   // 2 x 16 KB
  __shared__ _Float16 Bs[2][128 * 64];   // 2 x 16 KB
  __shared__ u64 t2[128][2][2];          // [tloc][wn][{k1,k2}]  4 KB

  const int tid = threadIdx.x;
  const int lane = tid & 63, w = tid >> 6;
  const int wm = w >> 1, wn = w & 1;
  // XCD swizzle: grid 2048, 8 XCDs -> each XCD owns exactly one cgroup
  const int swz = (blockIdx.x & 7) * 256 + (blockIdx.x >> 3);
  const int cg = swz >> 8, ttile = swz & 255;
  const int laneM = lane & 15, laneK = lane >> 4;
  const u64 zb = (u64)ttile * 65536;

  t2[tid >> 1][tid & 1][0] = ~0ull;
  t2[tid >> 1][tid & 1][1] = ~0ull;

  int offAh[4], offAl[4], offBh[4], offBl[4];
#pragma unroll
  for (int f = 0; f < 4; ++f) {
    int row = wm * 64 + f * 16 + laneM;
    offAh[f] = row * 64 + ((laneK ^ (row & 7)) * 8);
    offAl[f] = row * 64 + (((laneK + 4) ^ (row & 7)) * 8);
  }
#pragma unroll
  for (int g = 0; g < 4; ++g) {
    int row = wn * 64 + g * 16 + laneM;
    offBh[g] = row * 64 + ((laneK ^ (row & 7)) * 8);
    offBl[g] = row * 64 + (((laneK + 4) ^ (row & 7)) * 8);
  }

  float Areg[4][4];
#pragma unroll
  for (int f = 0; f < 4; ++f)
#pragma unroll
    for (int r = 0; r < 4; ++r)
      Areg[f][r] = An[ttile * 128 + wm * 64 + f * 16 + laneK * 4 + r];

  // prologue: stage step 0 into buf 0
  {
    const _Float16* sa = z16 + zb + tid * 8;
    const _Float16* sb = cb16 + (u64)(cg * 4) * 131072 + tid * 8;
#pragma unroll
    for (int t = 0; t < 4; ++t) GLOAD_LDS16(sa + t * 2048, &As[0][tid * 8 + t * 2048]);
#pragma unroll
    for (int t = 0; t < 4; ++t) GLOAD_LDS16(sb + t * 2048, &Bs[0][tid * 8 + t * 2048]);
  }
  __syncthreads();

  f32x4 acc[4][4];
#pragma unroll
  for (int f = 0; f < 4; ++f)
#pragma unroll
    for (int g = 0; g < 4; ++g) acc[f][g] = (f32x4){0.f, 0.f, 0.f, 0.f};

  for (int step = 0; step < 64; ++step) {
    const int buf = step & 1;
    const int sub = step >> 3, ks = step & 7;

    if (step < 63) {  // stage next step first (overlaps with compute below)
      const int ns = (step + 1) >> 3, nk = (step + 1) & 7;
      const _Float16* sa = z16 + zb + (u64)nk * 8192 + tid * 8;
      const _Float16* sb = cb16 + (u64)(cg * 4 + (ns >> 1)) * 131072 +
                           (u64)nk * 16384 + (u64)(ns & 1) * 8192 + tid * 8;
#pragma unroll
      for (int t = 0; t < 4; ++t) GLOAD_LDS16(sa + t * 2048, &As[buf ^ 1][tid * 8 + t * 2048]);
#pragma unroll
      for (int t = 0; t < 4; ++t) GLOAD_LDS16(sb + t * 2048, &Bs[buf ^ 1][tid * 8 + t * 2048]);
    }

    half8 ah[4], al[4];
#pragma unroll
    for (int f = 0; f < 4; ++f) {
      ah[f] = *reinterpret_cast<const half8*>(&As[buf][offAh[f]]);
      al[f] = *reinterpret_cast<const half8*>(&As[buf][offAl[f]]);
    }
#pragma unroll
    for (int g = 0; g < 4; ++g) {
      half8 bh = *reinterpret_cast<const half8*>(&Bs[buf][offBh[g]]);
      half8 bl = *reinterpret_cast<const half8*>(&Bs[buf][offBl[g]]);
#pragma unroll
      for (int f = 0; f < 4; ++f)
        acc[f][g] = __builtin_amdgcn_mfma_f32_16x16x32_f16(ah[f], bh, acc[f][g], 0, 0, 0);
#pragma unroll
      for (int f = 0; f < 4; ++f)
        acc[f][g] = __builtin_amdgcn_mfma_f32_16x16x32_f16(al[f], bh, acc[f][g], 0, 0, 0);
#pragma unroll
      for (int f = 0; f < 4; ++f)
        acc[f][g] = __builtin_amdgcn_mfma_f32_16x16x32_f16(ah[f], bl, acc[f][g], 0, 0, 0);
    }

    if (ks == 7) {  // sub complete: exact score chain + top-2 merge
      float Creg[4];
#pragma unroll
      for (int g = 0; g < 4; ++g)
        Creg[g] = Cn[cg * 1024 + sub * 128 + wn * 64 + g * 16 + laneM];
#pragma unroll
      for (int f = 0; f < 4; ++f) {
#pragma unroll
        for (int r = 0; r < 4; ++r) {
          const int tloc = wm * 64 + f * 16 + laneK * 4 + r;
          const float Ar = Areg[f][r];
          u64 k1 = ~0ull, k2 = ~0ull;
#pragma unroll
          for (int g = 0; g < 4; ++g) {
            float p2 = __fmul_rn(acc[f][g][r], 0x1p-15f);   // 2*dot, exact pow2
            float t1 = __fsub_rn(Ar, p2);
            float t  = __fadd_rn(t1, Creg[g]);
            u64 key = ((u64)__float_as_uint(t) << 32) |
                      (u64)(cg * 1024 + sub * 128 + wn * 64 + g * 16 + laneM);
            if (key < k1) { k2 = k1; k1 = key; }
            else if (key < k2) { k2 = key; }
          }
#pragma unroll
          for (int d = 8; d > 0; d >>= 1) {
            u64 o1 = __shfl_xor(k1, d);
            u64 o2 = __shfl_xor(k2, d);
            u64 n1 = (k1 < o1) ? k1 : o1;
            u64 hi = (k1 < o1) ? o1 : k1;
            u64 l2 = (k2 < o2) ? k2 : o2;
            k1 = n1; k2 = (hi < l2) ? hi : l2;
          }
          if (laneM == 0) {
            u64 s1 = t2[tloc][wn][0], s2 = t2[tloc][wn][1];
            u64 n1 = (s1 < k1) ? s1 : k1;
            u64 hi = (s1 < k1) ? k1 : s1;
            u64 l2 = (s2 < k2) ? s2 : k2;
            t2[tloc][wn][0] = n1;
            t2[tloc][wn][1] = (hi < l2) ? hi : l2;
          }
        }
      }
      // re-zero ALL accumulators for the next sub (the only acc reset)
#pragma unroll
      for (int f = 0; f < 4; ++f)
#pragma unroll
        for (int g = 0; g < 4; ++g) acc[f][g] = (f32x4){0.f, 0.f, 0.f, 0.f};
    }
    __syncthreads();
  }

  if (tid < 128) {
    u64 a1 = t2[tid][0][0], a2 = t2[tid][0][1];
    u64 b1 = t2[tid][1][0], b2 = t2[tid][1][1];
    u64 K1 = (a1 < b1) ? a1 : b1;
    u64 hi = (a1 < b1) ? b1 : a1;
    u64 l2 = (a2 < b2) ? a2 : b2;
    u64 K2 = (hi < l2) ? hi : l2;
    const int token = ttile * 128 + tid;
    pk1[(size_t)token * 8 + cg] = K1;
    pv2[(size_t)token * 8 + cg] = __uint_as_float((unsigned)(K2 >> 32));
  }
}

// ---- detect: merge 8 cgroup top-2, write candidate ids, flag near-ties ----
__global__ __launch_bounds__(256)
void vq_detect(const u64* __restrict__ pk1, const float* __restrict__ pv2,
               int* __restrict__ ids, int* __restrict__ rcnt, int* __restrict__ rlist) {
  const int token = blockIdx.x * 256 + threadIdx.x;
  u64 K1 = pk1[(size_t)token * 8];
  float V2 = pv2[(size_t)token * 8];
#pragma unroll
  for (int c = 1; c < 8; ++c) {
    u64 k1 = pk1[(size_t)token * 8 + c];
    float v2 = pv2[(size_t)token * 8 + c];
    u64 n1 = (k1 < K1) ? k1 : K1;
    u64 hi = (k1 < K1) ? K1 : k1;
    float loser = __uint_as_float((unsigned)(hi >> 32));
    V2 = fminf(fminf(V2, v2), loser);
    K1 = n1;
  }
  ids[token] = (int)(K1 & 0xffffffffull);
  float d1 = __uint_as_float((unsigned)(K1 >> 32));
  if (V2 - d1 < RESCUE_TAU) {
    int p = atomicAdd(rcnt, 1);
    rlist[p] = token;
  }
}

// ---- rescue: exact R3-chain rescan of flagged tokens over all codes ------
__global__ __launch_bounds__(256)
void vq_rescue(const float* __restrict__ z, const float* __restrict__ cb,
               const float* __restrict__ An, const float* __restrict__ Cn,
               const int* __restrict__ rcnt, const int* __restrict__ rlist,
               int* __restrict__ ids) {
  __shared__ float zrow[RPASS][256];
  __shared__ u64 red[256];
  const int tid = threadIdx.x;
  const int total = *rcnt;
  for (int base = blockIdx.x * RPASS; base < total; base += gridDim.x * RPASS) {
    const int np = min(RPASS, total - base);
    __syncthreads();
    for (int li = tid; li < np * 256; li += 256)
      zrow[li >> 8][li & 255] = z[(size_t)rlist[base + (li >> 8)] * DIM + (li & 255)];
    __syncthreads();
    float Atok[RPASS];
#pragma unroll
    for (int s = 0; s < RPASS; ++s) Atok[s] = (s < np) ? An[rlist[base + s]] : 0.f;
    u64 bkey[RPASS];
#pragma unroll
    for (int s = 0; s < RPASS; ++s) bkey[s] = ~0ull;
    for (int jj = 0; jj < KCB / 256; ++jj) {
      const int j = jj * 256 + tid;
      const float4* crow = reinterpret_cast<const float4*>(cb + (size_t)j * DIM);
      float dots[RPASS];
#pragma unroll
      for (int s = 0; s < RPASS; ++s) dots[s] = 0.f;
      for (int k4 = 0; k4 < 64; ++k4) {
        const float4 c4 = crow[k4];
#pragma unroll
        for (int s = 0; s < RPASS; ++s) {   // k ascending, same fmaf chain as R3
          const float4 z4 = *reinterpret_cast<const float4*>(&zrow[s][k4 * 4]);
          dots[s] = fmaf(z4.x, c4.x, dots[s]);
          dots[s] = fmaf(z4.y, c4.y, dots[s]);
          dots[s] = fmaf(z4.z, c4.z, dots[s]);
          dots[s] = fmaf(z4.w, c4.w, dots[s]);
        }
      }
      const float Cj = Cn[j];
#pragma unroll
      for (int s = 0; s < RPASS; ++s) {
        float p2 = __fmul_rn(2.0f, dots[s]);
        float t1 = __fsub_rn(Atok[s], p2);
        float t  = __fadd_rn(t1, Cj);
        u64 key = ((u64)__float_as_uint(t) << 32) | (u64)j;
        if (key < bkey[s]) bkey[s] = key;
      }
    }
    for (int s = 0; s < np; ++s) {
      __syncthreads();
      red[tid] = bkey[s];
      __syncthreads();
      for (int off = 128; off > 0; off >>= 1) {
        if (tid < off) { u64 o = red[tid + off]; if (o < red[tid]) red[tid] = o; }
        __syncthreads();
      }
      if (tid == 0) ids[rlist[base + s]] = (int)(red[0] & 0xffffffffull);
    }
  }
}

// ---- finalize: gather z_q, ids; block-reduced loss partials (no atomics) --
__global__ __launch_bounds__(256)
void vq_finalize_ids(const float* __restrict__ z, const float* __restrict__ cb,
                     const int* __restrict__ ids, float* __restrict__ out,
                     double* __restrict__ part) {
  __shared__ double sred[4];
  const int g64 = threadIdx.x >> 6, lane = threadIdx.x & 63;
  double s = 0.0;
#pragma unroll
  for (int i = 0; i < 4; ++i) {
    const int n = blockIdx.x * 16 + i * 4 + g64;
    const int bk = ids[n];
    const float4 c4 = *reinterpret_cast<const float4*>(&cb[(size_t)bk * DIM + lane * 4]);
    const float4 z4 = *reinterpret_cast<const float4*>(&z[(size_t)n * DIM + lane * 4]);
    *reinterpret_cast<float4*>(&out[(size_t)n * DIM + lane * 4]) = c4;
    float dx = __fsub_rn(c4.x, z4.x), dy = __fsub_rn(c4.y, z4.y);
    float dz = __fsub_rn(c4.z, z4.z), dw = __fsub_rn(c4.w, z4.w);
    s += (double)dx * dx + (double)dy * dy + (double)dz * dz + (double)dw * dw;
    if (lane == 0) out[(size_t)NTOK * DIM + n] = (float)bk;
  }
#pragma unroll
  for (int off = 32; off > 0; off >>= 1) s += __shfl_down(s, off);
  if (lane == 0) sred[g64] = s;
  __syncthreads();
  if (threadIdx.x == 0)
    part[blockIdx.x] = (sred[0] + sred[1]) + (sred[2] + sred[3]);
}

__global__ __launch_bounds__(256)
void vq_loss_write(const double* __restrict__ part, float* __restrict__ out) {
  __shared__ double red[256];
  double s = 0.0;
  for (int i = threadIdx.x; i < 2048; i += 256) s += part[i];
  red[threadIdx.x] = s;
  __syncthreads();
  for (int off = 128; off > 0; off >>= 1) {
    if (threadIdx.x < off) red[threadIdx.x] += red[threadIdx.x + off];
    __syncthreads();
  }
  if (threadIdx.x == 0)
    out[(size_t)NTOK * DIM + NTOK] =
        (float)(0.25 * red[0] / (double)((size_t)NTOK * DIM));
}

// ======================= R3 fallback path (ws too small) ==================
#define NCHUNK 8
#define CHUNK 1024
#define TT 128
#define CT 128
#define DC 32

__global__ __launch_bounds__(256)
void vq_argmin_kernel(const float* __restrict__ z, const float* __restrict__ cb,
                      const float* __restrict__ An, const float* __restrict__ Cn,
                      float* __restrict__ pv, int* __restrict__ pk) {
  __shared__ float zs[DC * TT];
  __shared__ float cs[DC * CT];
  const int tid = threadIdx.x;
  const int tx = tid & 15, ty = tid >> 4;
  const int chunk = blockIdx.x & 7;
  const int tile = blockIdx.x >> 3;
  const int base_t = tile * TT;
  const int base_k = chunk * CHUNK;
  float Areg[8];
#pragma unroll
  for (int i = 0; i < 8; ++i) Areg[i] = An[base_t + ty * 8 + i];
  float bestv[8]; int bestk[8];
#pragma unroll
  for (int i = 0; i < 8; ++i) { bestv[i] = INFINITY; bestk[i] = 0; }
  for (int st = 0; st < CHUNK / CT; ++st) {
    const int kb0 = base_k + st * CT;
    float acc[8][8];
#pragma unroll
    for (int i = 0; i < 8; ++i)
#pragma unroll
      for (int j = 0; j < 8; ++j) acc[i][j] = 0.f;
    for (int dc = 0; dc < DIM / DC; ++dc) {
      __syncthreads();
#pragma unroll
      for (int li = tid; li < DC * TT / 4; li += 256) {
        const int row = li >> 3;
        const int dv = li & 7;
        const int ibase = dv * 4 * 128 + (row ^ (dv << 2) ^ ((row & 32) >> 3));
        float4 v = *reinterpret_cast<const float4*>(
            &z[(size_t)(base_t + row) * DIM + dc * DC + dv * 4]);
        zs[ibase] = v.x; zs[ibase + 128] = v.y;
        zs[ibase + 256] = v.z; zs[ibase + 384] = v.w;
        float4 c = *reinterpret_cast<const float4*>(
            &cb[(size_t)(kb0 + row) * DIM + dc * DC + dv * 4]);
        cs[ibase] = c.x; cs[ibase + 128] = c.y;
        cs[ibase + 256] = c.z; cs[ibase + 384] = c.w;
      }
      __syncthreads();
#pragma unroll
      for (int dd = 0; dd < DC / 4; ++dd) {
        const int s1 = dd << 2;
        const float* zp0 = &zs[dd * 4 * 128 + ((ty * 8) ^ s1 ^ (ty & 4))];
        const float* zp1 = &zs[dd * 4 * 128 + ((ty * 8 + 4) ^ s1 ^ (ty & 4))];
        const float* cp0 = &cs[dd * 4 * 128 + ((tx * 8) ^ s1 ^ (tx & 4))];
        const float* cp1 = &cs[dd * 4 * 128 + ((tx * 8 + 4) ^ s1 ^ (tx & 4))];
#pragma unroll
        for (int q = 0; q < 4; ++q) {
          const float4 za  = *reinterpret_cast<const float4*>(zp0 + q * 128);
          const float4 zb  = *reinterpret_cast<const float4*>(zp1 + q * 128);
          const float4 ca  = *reinterpret_cast<const float4*>(cp0 + q * 128);
          const float4 cbv = *reinterpret_cast<const float4*>(cp1 + q * 128);
          const float zv[8] = {za.x, za.y, za.z, za.w, zb.x, zb.y, zb.z, zb.w};
          const float cv[8] = {ca.x, ca.y, ca.z, ca.w, cbv.x, cbv.y, cbv.z, cbv.w};
#pragma unroll
          for (int i = 0; i < 8; ++i)
#pragma unroll
            for (int j = 0; j < 8; ++j)
              acc[i][j] = fmaf(zv[i], cv[j], acc[i][j]);
        }
      }
    }
#pragma unroll
    for (int j = 0; j < 8; ++j) {
      const int klocal = st * CT + tx * 8 + j;
      const float Ck = Cn[base_k + klocal];
#pragma unroll
      for (int i = 0; i < 8; ++i) {
        float p2 = __fmul_rn(2.0f, acc[i][j]);
        float t1 = __fsub_rn(Areg[i], p2);
        float t  = __fadd_rn(t1, Ck);
        if (t < bestv[i]) { bestv[i] = t; bestk[i] = klocal; }
      }
    }
  }
  __syncthreads();
  float (*mv)[16] = reinterpret_cast<float(*)[16]>(zs);
  int   (*mk)[16] = reinterpret_cast<int(*)[16]>(zs + TT * 16);
#pragma unroll
  for (int i = 0; i < 8; ++i) { mv[ty * 8 + i][tx] = bestv[i]; mk[ty * 8 + i][tx] = bestk[i]; }
  __syncthreads();
  if (tid < TT) {
    float bv = mv[tid][0]; int bk = mk[tid][0];
#pragma unroll
    for (int x = 1; x < 16; ++x) {
      float v = mv[tid][x]; int k = mk[tid][x];
      if (v < bv || (v == bv && k < bk)) { bv = v; bk = k; }
    }
    size_t idx = (size_t)(base_t + tid) * NCHUNK + chunk;
    pv[idx] = bv;
    pk[idx] = base_k + bk;
  }
}

__global__ __launch_bounds__(256)
void vq_finalize(const float* __restrict__ z, const float* __restrict__ cb,
                 const float* __restrict__ pv, const int* __restrict__ pk,
                 float* __restrict__ out, double* __restrict__ loss_acc) {
  const int n = blockIdx.x * 4 + (threadIdx.x >> 6);
  const int lane = threadIdx.x & 63;
  float bv = INFINITY; int bk = 0;
#pragma unroll
  for (int c = 0; c < NCHUNK; ++c) {
    float v = pv[(size_t)n * NCHUNK + c];
    int k = pk[(size_t)n * NCHUNK + c];
    if (v < bv || (v == bv && k < bk)) { bv = v; bk = k; }
  }
  const float4 c4 = *reinterpret_cast<const float4*>(&cb[(size_t)bk * DIM + lane * 4]);
  const float4 z4 = *reinterpret_cast<const float4*>(&z[(size_t)n * DIM + lane * 4]);
  *reinterpret_cast<float4*>(&out[(size_t)n * DIM + lane * 4]) = c4;
  float dx = __fsub_rn(c4.x, z4.x), dy = __fsub_rn(c4.y, z4.y);
  float dz = __fsub_rn(c4.z, z4.z), dw = __fsub_rn(c4.w, z4.w);
  double s = (double)dx * dx + (double)dy * dy + (double)dz * dz + (double)dw * dw;
#pragma unroll
  for (int off = 32; off > 0; off >>= 1) s += __shfl_down(s, off);
  if (lane == 0) {
    out[(size_t)NTOK * DIM + n] = (float)bk;
    atomicAdd(loss_acc, s);
  }
}

__global__ void vq_loss_write_fb(const double* __restrict__ loss_acc, float* __restrict__ out) {
  out[(size_t)NTOK * DIM + NTOK] = (float)(0.25 * (*loss_acc) / (double)((size_t)NTOK * DIM));
}

// ==========================================================================
extern "C" void kernel_launch(void* const* d_in, const int* in_sizes, int n_in,
                              void* d_out, int out_size, void* d_ws, size_t ws_size,
                              hipStream_t stream) {
  const float* z  = (const float*)d_in[0];
  const float* cb = (const float*)d_in[1];
  float* out = (float*)d_out;
  char* ws = (char*)d_ws;

  if (ws_size >= WS_NEED) {
    float*     An   = (float*)(ws + OFF_AN);
    float*     Cn   = (float*)(ws + OFF_CN);
    int*       ids  = (int*)(ws + OFF_IDS);
    int*       rcnt = (int*)(ws + OFF_RCNT);
    int*       rlist= (int*)(ws + OFF_RLIST);
    double*    part = (double*)(ws + OFF_PART);
    u64*       pk1  = (u64*)(ws + OFF_PK1);
    float*     pv2  = (float*)(ws + OFF_PV2);
    _Float16*  z16  = (_Float16*)(ws + OFF_Z16);
    _Float16*  c16  = (_Float16*)(ws + OFF_CB16);

    hipMemsetAsync(rcnt, 0, 128, stream);
    rownorm256_np<<<NTOK / 256, 256, 0, stream>>>(z, An, NTOK);
    rownorm256_np<<<KCB / 256, 256, 0, stream>>>(cb, Cn, KCB);
    conv_z16<<<256 * 8, 128, 0, stream>>>(z, z16);
    conv_cb16<<<32 * 8, 256, 0, stream>>>(cb, c16);
    vq_mfma_top2<<<2048, 256, 0, stream>>>(z16, c16, An, Cn, pk1, pv2);
    vq_detect<<<NTOK / 256, 256, 0, stream>>>(pk1, pv2, ids, rcnt, rlist);
    vq_rescue<<<1024, 256, 0, stream>>>(z, cb, An, Cn, rcnt, rlist, ids);
    vq_finalize_ids<<<NTOK / 16, 256, 0, stream>>>(z, cb, ids, out, part);
    vq_loss_write<<<1, 256, 0, stream>>>(part, out);
  } else {
    // R3 fallback (needs ~2.26 MB)
    float*  An = (float*)(ws);
    float*  Cn = (float*)(ws + 131072);
    float*  pv = (float*)(ws + 163840);
    int*    pk = (int*)(ws + 1212416);
    double* loss = (double*)(ws + 2260992);
    hipMemsetAsync(loss, 0, sizeof(double), stream);
    rownorm256_np<<<NTOK / 256, 256, 0, stream>>>(z, An, NTOK);
    rownorm256_np<<<KCB / 256, 256, 0, stream>>>(cb, Cn, KCB);
    vq_argmin_kernel<<<(NTOK / TT) * NCHUNK, 256, 0, stream>>>(z, cb, An, Cn, pv, pk);
    vq_finalize<<<NTOK / 4, 256, 0, stream>>>(z, cb, pv, pk, out, loss);
    vq_loss_write_fb<<<1, 1, 0, stream>>>(loss, out);
  }
}

// Round 8
// 963.894 us; speedup vs baseline: 2.5489x; 1.0108x over previous
//
#include <hip/hip_runtime.h>
#include <math.h>

#define NTOK 32768
#define DIM 256
#define KCB 8192
#define RESCUE_TAU 1e-3f
#define RPASS 8

typedef _Float16 half8 __attribute__((ext_vector_type(8)));
typedef float f32x4 __attribute__((ext_vector_type(4)));
typedef unsigned long long u64;

// ---------------- fast-path ws layout (bytes) ----------------
#define OFF_AN    0ull
#define OFF_CN    131072ull
#define OFF_IDS   163840ull
#define OFF_RCNT  294912ull
#define OFF_RLIST 295040ull
#define OFF_PART  426112ull      // 2048 doubles
#define OFF_PK1   442496ull      // u64 [32768][8]
#define OFF_PV2   2539648ull     // f32 [32768][8]
#define OFF_Z16   3588224ull     // [256 tile][8 ks][128 row][64 halves swz]
#define OFF_CB16  37142656ull    // [32 tile][8 ks][256 row][64 halves swz]
#define WS_NEED   45531264ull

#define GLOAD_LDS16(gp, lp) __builtin_amdgcn_global_load_lds( \
    (const __attribute__((address_space(1))) void*)(gp), \
    (__attribute__((address_space(3))) void*)(lp), 16, 0, 0)

// ---- numpy-pairwise ||row||^2 (bitwise-matching np.sum(x*x,axis=1)) ------
__global__ __launch_bounds__(256)
void rownorm256_np(const float* __restrict__ M, float* __restrict__ out, int rows) {
  int r = blockIdx.x * 256 + threadIdx.x;
  if (r >= rows) return;
  const float* p = M + (size_t)r * DIM;
  float blk[2];
#pragma unroll
  for (int b = 0; b < 2; ++b) {
    const float* a = p + b * 128;
    float rr[8];
#pragma unroll
    for (int j = 0; j < 8; ++j) rr[j] = __fmul_rn(a[j], a[j]);
    for (int i = 8; i < 128; i += 8) {
#pragma unroll
      for (int j = 0; j < 8; ++j)
        rr[j] = __fadd_rn(rr[j], __fmul_rn(a[i + j], a[i + j]));
    }
    float s01 = __fadd_rn(rr[0], rr[1]);
    float s23 = __fadd_rn(rr[2], rr[3]);
    float s45 = __fadd_rn(rr[4], rr[5]);
    float s67 = __fadd_rn(rr[6], rr[7]);
    blk[b] = __fadd_rn(__fadd_rn(s01, s23), __fadd_rn(s45, s67));
  }
  out[r] = __fadd_rn(blk[0], blk[1]);
}

// ---- convert: fp32 -> scaled fp16 (hi,lo) pair, pre-swizzled tiled layout ----
__global__ __launch_bounds__(128)
void conv_z16(const float* __restrict__ z, _Float16* __restrict__ dst) {
  const int tile = blockIdx.x >> 3, ks = blockIdx.x & 7, row = threadIdx.x;
  const float* src = z + ((size_t)(tile * 128 + row)) * DIM + ks * 32;
  _Float16* d = dst + (u64)tile * 65536 + (u64)ks * 8192 + row * 64;
  const int rs = row & 7;
#pragma unroll
  for (int q = 0; q < 4; ++q) {
    half8 hv, lv;
#pragma unroll
    for (int j = 0; j < 8; ++j) {
      float f = src[q * 8 + j] * 64.0f;          // exact pow2 scale
      _Float16 h = (_Float16)f;                  // RNE
      float lf = f - (float)h;                   // exact
      hv[j] = h; lv[j] = (_Float16)lf;
    }
    *reinterpret_cast<half8*>(d + ((q ^ rs) * 8)) = hv;
    *reinterpret_cast<half8*>(d + (((q + 4) ^ rs) * 8)) = lv;
  }
}

__global__ __launch_bounds__(256)
void conv_cb16(const float* __restrict__ cb, _Float16* __restrict__ dst) {
  const int tile = blockIdx.x >> 3, ks = blockIdx.x & 7, row = threadIdx.x;
  const float* src = cb + ((size_t)(tile * 256 + row)) * DIM + ks * 32;
  _Float16* d = dst + (u64)tile * 131072 + (u64)ks * 16384 + row * 64;
  const int rs = row & 7;
#pragma unroll
  for (int q = 0; q < 4; ++q) {
    half8 hv, lv;
#pragma unroll
    for (int j = 0; j < 8; ++j) {
      float f = src[q * 8 + j] * 1024.0f;        // exact pow2 scale
      _Float16 h = (_Float16)f;
      float lf = f - (float)h;
      hv[j] = h; lv[j] = (_Float16)lf;
    }
    *reinterpret_cast<half8*>(d + ((q ^ rs) * 8)) = hv;
    *reinterpret_cast<half8*>(d + (((q + 4) ^ rs) * 8)) = lv;
  }
}

// ---- MFMA GEMM + per-cgroup top-2, statically-named double buffers -------
// Block: 128 tokens x 128 codes, 4 waves (2m x 2n), wave-tile 64x64.
// 64 steps = 8 subs x 8 ks (K=32). Unrolled x2 so buffers are DISTINCT LDS
// OBJECTS (As0/As1/Bs0/Bs1) -> compiler can prove gload_lds stores (next
// buffer) don't alias ds_reads (current buffer) -> no early vmcnt(0); loads
// drain only at the step-end barrier, hidden under the MFMA phase.
__global__ __launch_bounds__(256, 2)
void vq_mfma_top2(const _Float16* __restrict__ z16, const _Float16* __restrict__ cb16,
                  const float* __restrict__ An, const float* __restrict__ Cn,
                  u64* __restrict__ pk1, float* __restrict__ pv2) {
  __shared__ _Float16 As0[128 * 64];   // 16 KB each
  __shared__ _Float16 Bs0[128 * 64];
  __shared__ _Float16 As1[128 * 64];
  __shared__ _Float16 Bs1[128 * 64];
  __shared__ u64 t2[128][2][2];        // [tloc][wn][{k1,k2}]  4 KB

  const int tid = threadIdx.x;
  const int lane = tid & 63, w = tid >> 6;
  const int wm = w >> 1, wn = w & 1;
  // XCD swizzle: grid 2048, 8 XCDs -> each XCD owns exactly one cgroup
  const int swz = (blockIdx.x & 7) * 256 + (blockIdx.x >> 3);
  const int cg = swz >> 8, ttile = swz & 255;
  const int laneM = lane & 15, laneK = lane >> 4;
  const u64 zb = (u64)ttile * 65536;

  t2[tid >> 1][tid & 1][0] = ~0ull;
  t2[tid >> 1][tid & 1][1] = ~0ull;

  int offAh[4], offAl[4], offBh[4], offBl[4];
#pragma unroll
  for (int f = 0; f < 4; ++f) {
    int row = wm * 64 + f * 16 + laneM;
    offAh[f] = row * 64 + ((laneK ^ (row & 7)) * 8);
    offAl[f] = row * 64 + (((laneK + 4) ^ (row & 7)) * 8);
  }
#pragma unroll
  for (int g = 0; g < 4; ++g) {
    int row = wn * 64 + g * 16 + laneM;
    offBh[g] = row * 64 + ((laneK ^ (row & 7)) * 8);
    offBl[g] = row * 64 + (((laneK + 4) ^ (row & 7)) * 8);
  }

  // preload ALL epilogue constants (no global loads inside the main loop)
  float Areg[4][4];
#pragma unroll
  for (int f = 0; f < 4; ++f)
#pragma unroll
    for (int r = 0; r < 4; ++r)
      Areg[f][r] = An[ttile * 128 + wm * 64 + f * 16 + laneK * 4 + r];
  float CregAll[8][4];
#pragma unroll
  for (int sb = 0; sb < 8; ++sb)
#pragma unroll
    for (int g = 0; g < 4; ++g)
      CregAll[sb][g] = Cn[cg * 1024 + sb * 128 + wn * 64 + g * 16 + laneM];

#define STAGE_STEP(s, Ad, Bd) do {                                          \
    const int ns_ = (s) >> 3, nk_ = (s) & 7;                                \
    const _Float16* sa_ = z16 + zb + (u64)nk_ * 8192 + tid * 8;             \
    const _Float16* sb_ = cb16 + (u64)(cg * 4 + (ns_ >> 1)) * 131072 +      \
                          (u64)nk_ * 16384 + (u64)(ns_ & 1) * 8192 + tid * 8;\
    GLOAD_LDS16(sa_,          &Ad[tid * 8]);                                \
    GLOAD_LDS16(sa_ + 2048,   &Ad[tid * 8 + 2048]);                         \
    GLOAD_LDS16(sa_ + 4096,   &Ad[tid * 8 + 4096]);                         \
    GLOAD_LDS16(sa_ + 6144,   &Ad[tid * 8 + 6144]);                         \
    GLOAD_LDS16(sb_,          &Bd[tid * 8]);                                \
    GLOAD_LDS16(sb_ + 2048,   &Bd[tid * 8 + 2048]);                         \
    GLOAD_LDS16(sb_ + 4096,   &Bd[tid * 8 + 4096]);                         \
    GLOAD_LDS16(sb_ + 6144,   &Bd[tid * 8 + 6144]);                         \
  } while (0)

#define COMPUTE_STEP(Asrc, Bsrc) do {                                       \
    half8 ah[4], al[4];                                                     \
    _Pragma("unroll")                                                       \
    for (int f = 0; f < 4; ++f) {                                           \
      ah[f] = *reinterpret_cast<const half8*>(&Asrc[offAh[f]]);             \
      al[f] = *reinterpret_cast<const half8*>(&Asrc[offAl[f]]);             \
    }                                                                       \
    _Pragma("unroll")                                                       \
    for (int g = 0; g < 4; ++g) {                                           \
      half8 bh = *reinterpret_cast<const half8*>(&Bsrc[offBh[g]]);          \
      half8 bl = *reinterpret_cast<const half8*>(&Bsrc[offBl[g]]);          \
      _Pragma("unroll")                                                     \
      for (int f = 0; f < 4; ++f)                                           \
        acc[f][g] = __builtin_amdgcn_mfma_f32_16x16x32_f16(ah[f], bh, acc[f][g], 0, 0, 0); \
      _Pragma("unroll")                                                     \
      for (int f = 0; f < 4; ++f)                                           \
        acc[f][g] = __builtin_amdgcn_mfma_f32_16x16x32_f16(al[f], bh, acc[f][g], 0, 0, 0); \
      _Pragma("unroll")                                                     \
      for (int f = 0; f < 4; ++f)                                           \
        acc[f][g] = __builtin_amdgcn_mfma_f32_16x16x32_f16(ah[f], bl, acc[f][g], 0, 0, 0); \
    }                                                                       \
  } while (0)

  // prologue: stage step 0 into buf0
  STAGE_STEP(0, As0, Bs0);
  __syncthreads();

  f32x4 acc[4][4];
#pragma unroll
  for (int f = 0; f < 4; ++f)
#pragma unroll
    for (int g = 0; g < 4; ++g) acc[f][g] = (f32x4){0.f, 0.f, 0.f, 0.f};

  for (int it = 0; it < 32; ++it) {
    const int s0 = it * 2;
    // ---- even half: stage s0+1 -> buf1, compute buf0 ----
    STAGE_STEP(s0 + 1, As1, Bs1);
    COMPUTE_STEP(As0, Bs0);
    __syncthreads();   // drains buf1 loads; all waves done reading buf0

    // ---- odd half: stage s0+2 -> buf0, compute buf1 ----
    if (it < 31) STAGE_STEP(s0 + 2, As0, Bs0);
    COMPUTE_STEP(As1, Bs1);

    if ((it & 3) == 3) {  // sub complete at odd step: score + top-2 merge
      const int sub = (s0 + 1) >> 3;
#pragma unroll
      for (int f = 0; f < 4; ++f) {
#pragma unroll
        for (int r = 0; r < 4; ++r) {
          const int tloc = wm * 64 + f * 16 + laneK * 4 + r;
          const float Ar = Areg[f][r];
          u64 k1 = ~0ull, k2 = ~0ull;
#pragma unroll
          for (int g = 0; g < 4; ++g) {
            float p2 = __fmul_rn(acc[f][g][r], 0x1p-15f);   // 2*dot, exact pow2
            float t1 = __fsub_rn(Ar, p2);
            float t  = __fadd_rn(t1, CregAll[sub][g]);
            u64 key = ((u64)__float_as_uint(t) << 32) |
                      (u64)(cg * 1024 + sub * 128 + wn * 64 + g * 16 + laneM);
            if (key < k1) { k2 = k1; k1 = key; }
            else if (key < k2) { k2 = key; }
          }
#pragma unroll
          for (int d = 8; d > 0; d >>= 1) {
            u64 o1 = __shfl_xor(k1, d);
            u64 o2 = __shfl_xor(k2, d);
            u64 n1 = (k1 < o1) ? k1 : o1;
            u64 hi = (k1 < o1) ? o1 : k1;
            u64 l2 = (k2 < o2) ? k2 : o2;
            k1 = n1; k2 = (hi < l2) ? hi : l2;
          }
          if (laneM == 0) {
            u64 s1 = t2[tloc][wn][0], s2 = t2[tloc][wn][1];
            u64 n1 = (s1 < k1) ? s1 : k1;
            u64 hi = (s1 < k1) ? k1 : s1;
            u64 l2 = (s2 < k2) ? s2 : k2;
            t2[tloc][wn][0] = n1;
            t2[tloc][wn][1] = (hi < l2) ? hi : l2;
          }
        }
      }
      // re-zero ALL accumulators for the next sub
#pragma unroll
      for (int f = 0; f < 4; ++f)
#pragma unroll
        for (int g = 0; g < 4; ++g) acc[f][g] = (f32x4){0.f, 0.f, 0.f, 0.f};
    }
    __syncthreads();   // drains buf0 loads; all waves done reading buf1
  }

#undef STAGE_STEP
#undef COMPUTE_STEP

  if (tid < 128) {
    u64 a1 = t2[tid][0][0], a2 = t2[tid][0][1];
    u64 b1 = t2[tid][1][0], b2 = t2[tid][1][1];
    u64 K1 = (a1 < b1) ? a1 : b1;
    u64 hi = (a1 < b1) ? b1 : a1;
    u64 l2 = (a2 < b2) ? a2 : b2;
    u64 K2 = (hi < l2) ? hi : l2;
    const int token = ttile * 128 + tid;
    pk1[(size_t)token * 8 + cg] = K1;
    pv2[(size_t)token * 8 + cg] = __uint_as_float((unsigned)(K2 >> 32));
  }
}

// ---- detect: merge 8 cgroup top-2, write candidate ids, flag near-ties ----
__global__ __launch_bounds__(256)
void vq_detect(const u64* __restrict__ pk1, const float* __restrict__ pv2,
               int* __restrict__ ids, int* __restrict__ rcnt, int* __restrict__ rlist) {
  const int token = blockIdx.x * 256 + threadIdx.x;
  u64 K1 = pk1[(size_t)token * 8];
  float V2 = pv2[(size_t)token * 8];
#pragma unroll
  for (int c = 1; c < 8; ++c) {
    u64 k1 = pk1[(size_t)token * 8 + c];
    float v2 = pv2[(size_t)token * 8 + c];
    u64 n1 = (k1 < K1) ? k1 : K1;
    u64 hi = (k1 < K1) ? K1 : k1;
    float loser = __uint_as_float((unsigned)(hi >> 32));
    V2 = fminf(fminf(V2, v2), loser);
    K1 = n1;
  }
  ids[token] = (int)(K1 & 0xffffffffull);
  float d1 = __uint_as_float((unsigned)(K1 >> 32));
  if (V2 - d1 < RESCUE_TAU) {
    int p = atomicAdd(rcnt, 1);
    rlist[p] = token;
  }
}

// ---- rescue: exact R3-chain rescan of flagged tokens over all codes ------
__global__ __launch_bounds__(256)
void vq_rescue(const float* __restrict__ z, const float* __restrict__ cb,
               const float* __restrict__ An, const float* __restrict__ Cn,
               const int* __restrict__ rcnt, const int* __restrict__ rlist,
               int* __restrict__ ids) {
  __shared__ float zrow[RPASS][256];
  __shared__ u64 red[256];
  const int tid = threadIdx.x;
  const int total = *rcnt;
  for (int base = blockIdx.x * RPASS; base < total; base += gridDim.x * RPASS) {
    const int np = min(RPASS, total - base);
    __syncthreads();
    for (int li = tid; li < np * 256; li += 256)
      zrow[li >> 8][li & 255] = z[(size_t)rlist[base + (li >> 8)] * DIM + (li & 255)];
    __syncthreads();
    float Atok[RPASS];
#pragma unroll
    for (int s = 0; s < RPASS; ++s) Atok[s] = (s < np) ? An[rlist[base + s]] : 0.f;
    u64 bkey[RPASS];
#pragma unroll
    for (int s = 0; s < RPASS; ++s) bkey[s] = ~0ull;
    for (int jj = 0; jj < KCB / 256; ++jj) {
      const int j = jj * 256 + tid;
      const float4* crow = reinterpret_cast<const float4*>(cb + (size_t)j * DIM);
      float dots[RPASS];
#pragma unroll
      for (int s = 0; s < RPASS; ++s) dots[s] = 0.f;
      for (int k4 = 0; k4 < 64; ++k4) {
        const float4 c4 = crow[k4];
#pragma unroll
        for (int s = 0; s < RPASS; ++s) {   // k ascending, same fmaf chain as R3
          const float4 z4 = *reinterpret_cast<const float4*>(&zrow[s][k4 * 4]);
          dots[s] = fmaf(z4.x, c4.x, dots[s]);
          dots[s] = fmaf(z4.y, c4.y, dots[s]);
          dots[s] = fmaf(z4.z, c4.z, dots[s]);
          dots[s] = fmaf(z4.w, c4.w, dots[s]);
        }
      }
      const float Cj = Cn[j];
#pragma unroll
      for (int s = 0; s < RPASS; ++s) {
        float p2 = __fmul_rn(2.0f, dots[s]);
        float t1 = __fsub_rn(Atok[s], p2);
        float t  = __fadd_rn(t1, Cj);
        u64 key = ((u64)__float_as_uint(t) << 32) | (u64)j;
        if (key < bkey[s]) bkey[s] = key;
      }
    }
    for (int s = 0; s < np; ++s) {
      __syncthreads();
      red[tid] = bkey[s];
      __syncthreads();
      for (int off = 128; off > 0; off >>= 1) {
        if (tid < off) { u64 o = red[tid + off]; if (o < red[tid]) red[tid] = o; }
        __syncthreads();
      }
      if (tid == 0) ids[rlist[base + s]] = (int)(red[0] & 0xffffffffull);
    }
  }
}

// ---- finalize: gather z_q, ids; block-reduced loss partials (no atomics) --
__global__ __launch_bounds__(256)
void vq_finalize_ids(const float* __restrict__ z, const float* __restrict__ cb,
                     const int* __restrict__ ids, float* __restrict__ out,
                     double* __restrict__ part) {
  __shared__ double sred[4];
  const int g64 = threadIdx.x >> 6, lane = threadIdx.x & 63;
  double s = 0.0;
#pragma unroll
  for (int i = 0; i < 4; ++i) {
    const int n = blockIdx.x * 16 + i * 4 + g64;
    const int bk = ids[n];
    const float4 c4 = *reinterpret_cast<const float4*>(&cb[(size_t)bk * DIM + lane * 4]);
    const float4 z4 = *reinterpret_cast<const float4*>(&z[(size_t)n * DIM + lane * 4]);
    *reinterpret_cast<float4*>(&out[(size_t)n * DIM + lane * 4]) = c4;
    float dx = __fsub_rn(c4.x, z4.x), dy = __fsub_rn(c4.y, z4.y);
    float dz = __fsub_rn(c4.z, z4.z), dw = __fsub_rn(c4.w, z4.w);
    s += (double)dx * dx + (double)dy * dy + (double)dz * dz + (double)dw * dw;
    if (lane == 0) out[(size_t)NTOK * DIM + n] = (float)bk;
  }
#pragma unroll
  for (int off = 32; off > 0; off >>= 1) s += __shfl_down(s, off);
  if (lane == 0) sred[g64] = s;
  __syncthreads();
  if (threadIdx.x == 0)
    part[blockIdx.x] = (sred[0] + sred[1]) + (sred[2] + sred[3]);
}

__global__ __launch_bounds__(256)
void vq_loss_write(const double* __restrict__ part, float* __restrict__ out) {
  __shared__ double red[256];
  double s = 0.0;
  for (int i = threadIdx.x; i < 2048; i += 256) s += part[i];
  red[threadIdx.x] = s;
  __syncthreads();
  for (int off = 128; off > 0; off >>= 1) {
    if (threadIdx.x < off) red[threadIdx.x] += red[threadIdx.x + off];
    __syncthreads();
  }
  if (threadIdx.x == 0)
    out[(size_t)NTOK * DIM + NTOK] =
        (float)(0.25 * red[0] / (double)((size_t)NTOK * DIM));
}

// ======================= R3 fallback path (ws too small) ==================
#define NCHUNK 8
#define CHUNK 1024
#define TT 128
#define CT 128
#define DC 32

__global__ __launch_bounds__(256)
void vq_argmin_kernel(const float* __restrict__ z, const float* __restrict__ cb,
                      const float* __restrict__ An, const float* __restrict__ Cn,
                      float* __restrict__ pv, int* __restrict__ pk) {
  __shared__ float zs[DC * TT];
  __shared__ float cs[DC * CT];
  const int tid = threadIdx.x;
  const int tx = tid & 15, ty = tid >> 4;
  const int chunk = blockIdx.x & 7;
  const int tile = blockIdx.x >> 3;
  const int base_t = tile * TT;
  const int base_k = chunk * CHUNK;
  float Areg[8];
#pragma unroll
  for (int i = 0; i < 8; ++i) Areg[i] = An[base_t + ty * 8 + i];
  float bestv[8]; int bestk[8];
#pragma unroll
  for (int i = 0; i < 8; ++i) { bestv[i] = INFINITY; bestk[i] = 0; }
  for (int st = 0; st < CHUNK / CT; ++st) {
    const int kb0 = base_k + st * CT;
    float acc[8][8];
#pragma unroll
    for (int i = 0; i < 8; ++i)
#pragma unroll
      for (int j = 0; j < 8; ++j) acc[i][j] = 0.f;
    for (int dc = 0; dc < DIM / DC; ++dc) {
      __syncthreads();
#pragma unroll
      for (int li = tid; li < DC * TT / 4; li += 256) {
        const int row = li >> 3;
        const int dv = li & 7;
        const int ibase = dv * 4 * 128 + (row ^ (dv << 2) ^ ((row & 32) >> 3));
        float4 v = *reinterpret_cast<const float4*>(
            &z[(size_t)(base_t + row) * DIM + dc * DC + dv * 4]);
        zs[ibase] = v.x; zs[ibase + 128] = v.y;
        zs[ibase + 256] = v.z; zs[ibase + 384] = v.w;
        float4 c = *reinterpret_cast<const float4*>(
            &cb[(size_t)(kb0 + row) * DIM + dc * DC + dv * 4]);
        cs[ibase] = c.x; cs[ibase + 128] = c.y;
        cs[ibase + 256] = c.z; cs[ibase + 384] = c.w;
      }
      __syncthreads();
#pragma unroll
      for (int dd = 0; dd < DC / 4; ++dd) {
        const int s1 = dd << 2;
        const float* zp0 = &zs[dd * 4 * 128 + ((ty * 8) ^ s1 ^ (ty & 4))];
        const float* zp1 = &zs[dd * 4 * 128 + ((ty * 8 + 4) ^ s1 ^ (ty & 4))];
        const float* cp0 = &cs[dd * 4 * 128 + ((tx * 8) ^ s1 ^ (tx & 4))];
        const float* cp1 = &cs[dd * 4 * 128 + ((tx * 8 + 4) ^ s1 ^ (tx & 4))];
#pragma unroll
        for (int q = 0; q < 4; ++q) {
          const float4 za  = *reinterpret_cast<const float4*>(zp0 + q * 128);
          const float4 zb  = *reinterpret_cast<const float4*>(zp1 + q * 128);
          const float4 ca  = *reinterpret_cast<const float4*>(cp0 + q * 128);
          const float4 cbv = *reinterpret_cast<const float4*>(cp1 + q * 128);
          const float zv[8] = {za.x, za.y, za.z, za.w, zb.x, zb.y, zb.z, zb.w};
          const float cv[8] = {ca.x, ca.y, ca.z, ca.w, cbv.x, cbv.y, cbv.z, cbv.w};
#pragma unroll
          for (int i = 0; i < 8; ++i)
#pragma unroll
            for (int j = 0; j < 8; ++j)
              acc[i][j] = fmaf(zv[i], cv[j], acc[i][j]);
        }
      }
    }
#pragma unroll
    for (int j = 0; j < 8; ++j) {
      const int klocal = st * CT + tx * 8 + j;
      const float Ck = Cn[base_k + klocal];
#pragma unroll
      for (int i = 0; i < 8; ++i) {
        float p2 = __fmul_rn(2.0f, acc[i][j]);
        float t1 = __fsub_rn(Areg[i], p2);
        float t  = __fadd_rn(t1, Ck);
        if (t < bestv[i]) { bestv[i] = t; bestk[i] = klocal; }
      }
    }
  }
  __syncthreads();
  float (*mv)[16] = reinterpret_cast<float(*)[16]>(zs);
  int   (*mk)[16] = reinterpret_cast<int(*)[16]>(zs + TT * 16);
#pragma unroll
  for (int i = 0; i < 8; ++i) { mv[ty * 8 + i][tx] = bestv[i]; mk[ty * 8 + i][tx] = bestk[i]; }
  __syncthreads();
  if (tid < TT) {
    float bv = mv[tid][0]; int bk = mk[tid][0];
#pragma unroll
    for (int x = 1; x < 16; ++x) {
      float v = mv[tid][x]; int k = mk[tid][x];
      if (v < bv || (v == bv && k < bk)) { bv = v; bk = k; }
    }
    size_t idx = (size_t)(base_t + tid) * NCHUNK + chunk;
    pv[idx] = bv;
    pk[idx] = base_k + bk;
  }
}

__global__ __launch_bounds__(256)
void vq_finalize(const float* __restrict__ z, const float* __restrict__ cb,
                 const float* __restrict__ pv, const int* __restrict__ pk,
                 float* __restrict__ out, double* __restrict__ loss_acc) {
  const int n = blockIdx.x * 4 + (threadIdx.x >> 6);
  const int lane = threadIdx.x & 63;
  float bv = INFINITY; int bk = 0;
#pragma unroll
  for (int c = 0; c < NCHUNK; ++c) {
    float v = pv[(size_t)n * NCHUNK + c];
    int k = pk[(size_t)n * NCHUNK + c];
    if (v < bv || (v == bv && k < bk)) { bv = v; bk = k; }
  }
  const float4 c4 = *reinterpret_cast<const float4*>(&cb[(size_t)bk * DIM + lane * 4]);
  const float4 z4 = *reinterpret_cast<const float4*>(&z[(size_t)n * DIM + lane * 4]);
  *reinterpret_cast<float4*>(&out[(size_t)n * DIM + lane * 4]) = c4;
  float dx = __fsub_rn(c4.x, z4.x), dy = __fsub_rn(c4.y, z4.y);
  float dz = __fsub_rn(c4.z, z4.z), dw = __fsub_rn(c4.w, z4.w);
  double s = (double)dx * dx + (double)dy * dy + (double)dz * dz + (double)dw * dw;
#pragma unroll
  for (int off = 32; off > 0; off >>= 1) s += __shfl_down(s, off);
  if (lane == 0) {
    out[(size_t)NTOK * DIM + n] = (float)bk;
    atomicAdd(loss_acc, s);
  }
}

__global__ void vq_loss_write_fb(const double* __restrict__ loss_acc, float* __restrict__ out) {
  out[(size_t)NTOK * DIM + NTOK] = (float)(0.25 * (*loss_acc) / (double)((size_t)NTOK * DIM));
}

// ==========================================================================
extern "C" void kernel_launch(void* const* d_in, const int* in_sizes, int n_in,
                              void* d_out, int out_size, void* d_ws, size_t ws_size,
                              hipStream_t stream) {
  const float* z  = (const float*)d_in[0];
  const float* cb = (const float*)d_in[1];
  float* out = (float*)d_out;
  char* ws = (char*)d_ws;

  if (ws_size >= WS_NEED) {
    float*     An   = (float*)(ws + OFF_AN);
    float*     Cn   = (float*)(ws + OFF_CN);
    int*       ids  = (int*)(ws + OFF_IDS);
    int*       rcnt = (int*)(ws + OFF_RCNT);
    int*       rlist= (int*)(ws + OFF_RLIST);
    double*    part = (double*)(ws + OFF_PART);
    u64*       pk1  = (u64*)(ws + OFF_PK1);
    float*     pv2  = (float*)(ws + OFF_PV2);
    _Float16*  z16  = (_Float16*)(ws + OFF_Z16);
    _Float16*  c16  = (_Float16*)(ws + OFF_CB16);

    hipMemsetAsync(rcnt, 0, 128, stream);
    rownorm256_np<<<NTOK / 256, 256, 0, stream>>>(z, An, NTOK);
    rownorm256_np<<<KCB / 256, 256, 0, stream>>>(cb, Cn, KCB);
    conv_z16<<<256 * 8, 128, 0, stream>>>(z, z16);
    conv_cb16<<<32 * 8, 256, 0, stream>>>(cb, c16);
    vq_mfma_top2<<<2048, 256, 0, stream>>>(z16, c16, An, Cn, pk1, pv2);
    vq_detect<<<NTOK / 256, 256, 0, stream>>>(pk1, pv2, ids, rcnt, rlist);
    vq_rescue<<<1024, 256, 0, stream>>>(z, cb, An, Cn, rcnt, rlist, ids);
    vq_finalize_ids<<<NTOK / 16, 256, 0, stream>>>(z, cb, ids, out, part);
    vq_loss_write<<<1, 256, 0, stream>>>(part, out);
  } else {
    // R3 fallback (needs ~2.26 MB)
    float*  An = (float*)(ws);
    float*  Cn = (float*)(ws + 131072);
    float*  pv = (float*)(ws + 163840);
    int*    pk = (int*)(ws + 1212416);
    double* loss = (double*)(ws + 2260992);
    hipMemsetAsync(loss, 0, sizeof(double), stream);
    rownorm256_np<<<NTOK / 256, 256, 0, stream>>>(z, An, NTOK);
    rownorm256_np<<<KCB / 256, 256, 0, stream>>>(cb, Cn, KCB);
    vq_argmin_kernel<<<(NTOK / TT) * NCHUNK, 256, 0, stream>>>(z, cb, An, Cn, pv, pk);
    vq_finalize<<<NTOK / 4, 256, 0, stream>>>(z, cb, pv, pk, out, loss);
    vq_loss_write_fb<<<1, 1, 0, stream>>>(loss, out);
  }
}

// Round 9
// 812.729 us; speedup vs baseline: 3.0230x; 1.1860x over previous
//
#include <hip/hip_runtime.h>
#include <math.h>

#define NTOK 32768
#define DIM 256
#define KCB 8192
#define RESCUE_TAU 1e-3f
#define RPASS 8

typedef _Float16 half8 __attribute__((ext_vector_type(8)));
typedef float f32x4 __attribute__((ext_vector_type(4)));
typedef unsigned long long u64;
typedef unsigned int u32;

// ---------------- fast-path ws layout (bytes) ----------------
#define OFF_AN    0ull
#define OFF_CN    131072ull
#define OFF_IDS   163840ull
#define OFF_RCNT  294912ull
#define OFF_RLIST 295040ull
#define OFF_PART  426112ull      // 2048 doubles
#define OFF_PK1   442496ull      // u64 [32768][8]
#define OFF_PV2   2539648ull     // f32 [32768][8]
#define OFF_Z16   3588224ull     // [256 tile][8 ks][128 row][64 halves swz]
#define OFF_CB16  37142656ull    // [32 tile][8 ks][256 row][64 halves swz]
#define WS_NEED   45531264ull

#define GLOAD_LDS16(gp, lp) __builtin_amdgcn_global_load_lds( \
    (const __attribute__((address_space(1))) void*)(gp), \
    (__attribute__((address_space(3))) void*)(lp), 16, 0, 0)

static __device__ __forceinline__ u64 umin64(u64 a, u64 b) { return a < b ? a : b; }
static __device__ __forceinline__ u64 umax64(u64 a, u64 b) { return a < b ? b : a; }

// ---- numpy-pairwise ||row||^2 (bitwise-matching np.sum(x*x,axis=1)) ------
__global__ __launch_bounds__(256)
void rownorm256_np(const float* __restrict__ M, float* __restrict__ out, int rows) {
  int r = blockIdx.x * 256 + threadIdx.x;
  if (r >= rows) return;
  const float* p = M + (size_t)r * DIM;
  float blk[2];
#pragma unroll
  for (int b = 0; b < 2; ++b) {
    const float* a = p + b * 128;
    float rr[8];
#pragma unroll
    for (int j = 0; j < 8; ++j) rr[j] = __fmul_rn(a[j], a[j]);
    for (int i = 8; i < 128; i += 8) {
#pragma unroll
      for (int j = 0; j < 8; ++j)
        rr[j] = __fadd_rn(rr[j], __fmul_rn(a[i + j], a[i + j]));
    }
    float s01 = __fadd_rn(rr[0], rr[1]);
    float s23 = __fadd_rn(rr[2], rr[3]);
    float s45 = __fadd_rn(rr[4], rr[5]);
    float s67 = __fadd_rn(rr[6], rr[7]);
    blk[b] = __fadd_rn(__fadd_rn(s01, s23), __fadd_rn(s45, s67));
  }
  out[r] = __fadd_rn(blk[0], blk[1]);
}

// ---- convert: fp32 -> scaled fp16 (hi,lo) pair, pre-swizzled tiled layout ----
__global__ __launch_bounds__(128)
void conv_z16(const float* __restrict__ z, _Float16* __restrict__ dst) {
  const int tile = blockIdx.x >> 3, ks = blockIdx.x & 7, row = threadIdx.x;
  const float* src = z + ((size_t)(tile * 128 + row)) * DIM + ks * 32;
  _Float16* d = dst + (u64)tile * 65536 + (u64)ks * 8192 + row * 64;
  const int rs = row & 7;
#pragma unroll
  for (int q = 0; q < 4; ++q) {
    half8 hv, lv;
#pragma unroll
    for (int j = 0; j < 8; ++j) {
      float f = src[q * 8 + j] * 64.0f;          // exact pow2 scale
      _Float16 h = (_Float16)f;                  // RNE
      float lf = f - (float)h;                   // exact
      hv[j] = h; lv[j] = (_Float16)lf;
    }
    *reinterpret_cast<half8*>(d + ((q ^ rs) * 8)) = hv;
    *reinterpret_cast<half8*>(d + (((q + 4) ^ rs) * 8)) = lv;
  }
}

__global__ __launch_bounds__(256)
void conv_cb16(const float* __restrict__ cb, _Float16* __restrict__ dst) {
  const int tile = blockIdx.x >> 3, ks = blockIdx.x & 7, row = threadIdx.x;
  const float* src = cb + ((size_t)(tile * 256 + row)) * DIM + ks * 32;
  _Float16* d = dst + (u64)tile * 131072 + (u64)ks * 16384 + row * 64;
  const int rs = row & 7;
#pragma unroll
  for (int q = 0; q < 4; ++q) {
    half8 hv, lv;
#pragma unroll
    for (int j = 0; j < 8; ++j) {
      float f = src[q * 8 + j] * 1024.0f;        // exact pow2 scale
      _Float16 h = (_Float16)f;
      float lf = f - (float)h;
      hv[j] = h; lv[j] = (_Float16)lf;
    }
    *reinterpret_cast<half8*>(d + ((q ^ rs) * 8)) = hv;
    *reinterpret_cast<half8*>(d + (((q + 4) ^ rs) * 8)) = lv;
  }
}

// ---- MFMA GEMM + per-LANE top-2 ------------------------------------------
// Block: 128 tokens x 128 codes, 4 waves (2m x 2n), wave-tile 64x64.
// A (z16) loads DIRECTLY global->VGPR (reg double-buffered; layout is
// fragment-contiguous, 16B/lane). Only B goes through LDS (static dbuf).
// Epilogue: per-lane running top-2 over 16 token-slots (uint bit-compare,
// valid since distances > 0); single cross-lane reduce at kernel end.
// Ties => v2==v1 => margin 0 => rescued, so semantics match R8 exactly.
__global__ __launch_bounds__(256, 2)
void vq_mfma_top2(const _Float16* __restrict__ z16, const _Float16* __restrict__ cb16,
                  const float* __restrict__ An, const float* __restrict__ Cn,
                  u64* __restrict__ pk1, float* __restrict__ pv2) {
  __shared__ _Float16 Bs0[128 * 64];   // 16 KB
  __shared__ _Float16 Bs1[128 * 64];   // 16 KB
  __shared__ float    Cs[1024];        // 4 KB  (this cg's code norms)
  __shared__ u64      t2k[128][2];     // 2 KB
  __shared__ u32      t2v[128][2];     // 1 KB

  const int tid = threadIdx.x;
  const int lane = tid & 63, w = tid >> 6;
  const int wm = w >> 1, wn = w & 1;
  // XCD swizzle: grid 2048, 8 XCDs -> each XCD owns exactly one cgroup
  const int swz = (blockIdx.x & 7) * 256 + (blockIdx.x >> 3);
  const int cg = swz >> 8, ttile = swz & 255;
  const int laneM = lane & 15, laneK = lane >> 4;
  const _Float16* zt = z16 + (u64)ttile * 65536;

  // A-fragment per-lane offsets (halves) within a (tile,ks) 8KB plane-pair
  int offA[8];
#pragma unroll
  for (int f = 0; f < 4; ++f) {
    int row = wm * 64 + f * 16 + laneM;
    offA[f]     = row * 64 + ((laneK ^ (row & 7)) * 8);        // hi plane
    offA[f + 4] = row * 64 + (((laneK + 4) ^ (row & 7)) * 8);  // lo plane
  }
  int offBh[4], offBl[4];
#pragma unroll
  for (int g = 0; g < 4; ++g) {
    int row = wn * 64 + g * 16 + laneM;
    offBh[g] = row * 64 + ((laneK ^ (row & 7)) * 8);
    offBl[g] = row * 64 + (((laneK + 4) ^ (row & 7)) * 8);
  }

  // token norms (per-lane float4 loads)
  float Areg[4][4];
#pragma unroll
  for (int f = 0; f < 4; ++f) {
    float4 a4 = *reinterpret_cast<const float4*>(
        &An[ttile * 128 + wm * 64 + f * 16 + laneK * 4]);
    Areg[f][0] = a4.x; Areg[f][1] = a4.y; Areg[f][2] = a4.z; Areg[f][3] = a4.w;
  }
  // stage this cg's code norms into LDS (runtime-sub indexing -> LDS not regs)
  {
    float4 c4 = *reinterpret_cast<const float4*>(&Cn[cg * 1024 + tid * 4]);
    *reinterpret_cast<float4*>(&Cs[tid * 4]) = c4;
  }

  // per-lane top-2 state: 16 token-slots
  u32 v1b[16], v2b[16], c1v[16];
#pragma unroll
  for (int s = 0; s < 16; ++s) { v1b[s] = 0x7F800000u; v2b[s] = 0x7F800000u; c1v[s] = 0; }
  u32 codeSub = (u32)(cg * 1024 + wn * 64 + laneM);  // += 128 per sub

#define LOAD_A(dst, s) do {                                                  \
    const _Float16* ab_ = zt + (u64)((s) & 7) * 8192;                        \
    _Pragma("unroll")                                                        \
    for (int f_ = 0; f_ < 8; ++f_)                                           \
      dst[f_] = *reinterpret_cast<const half8*>(ab_ + offA[f_]);             \
  } while (0)

#define STAGE_B(s, Bd) do {                                                  \
    const int ns_ = (s) >> 3, nk_ = (s) & 7;                                 \
    const _Float16* sb_ = cb16 + (u64)(cg * 4 + (ns_ >> 1)) * 131072 +       \
                          (u64)nk_ * 16384 + (u64)(ns_ & 1) * 8192 + tid * 8;\
    GLOAD_LDS16(sb_,        &Bd[tid * 8]);                                   \
    GLOAD_LDS16(sb_ + 2048, &Bd[tid * 8 + 2048]);                            \
    GLOAD_LDS16(sb_ + 4096, &Bd[tid * 8 + 4096]);                            \
    GLOAD_LDS16(sb_ + 6144, &Bd[tid * 8 + 6144]);                            \
  } while (0)

#define COMPUTE(Asrc, Bsrc) do {                                             \
    _Pragma("unroll")                                                        \
    for (int g_ = 0; g_ < 4; ++g_) {                                         \
      half8 bh = *reinterpret_cast<const half8*>(&Bsrc[offBh[g_]]);          \
      half8 bl = *reinterpret_cast<const half8*>(&Bsrc[offBl[g_]]);          \
      _Pragma("unroll")                                                      \
      for (int f_ = 0; f_ < 4; ++f_)                                         \
        acc[f_][g_] = __builtin_amdgcn_mfma_f32_16x16x32_f16(Asrc[f_], bh, acc[f_][g_], 0, 0, 0);     \
      _Pragma("unroll")                                                      \
      for (int f_ = 0; f_ < 4; ++f_)                                         \
        acc[f_][g_] = __builtin_amdgcn_mfma_f32_16x16x32_f16(Asrc[f_ + 4], bh, acc[f_][g_], 0, 0, 0); \
      _Pragma("unroll")                                                      \
      for (int f_ = 0; f_ < 4; ++f_)                                         \
        acc[f_][g_] = __builtin_amdgcn_mfma_f32_16x16x32_f16(Asrc[f_], bl, acc[f_][g_], 0, 0, 0);     \
    }                                                                        \
  } while (0)

  half8 aCur[8], aNxt[8];
  LOAD_A(aCur, 0);
  STAGE_B(0, Bs0);
  __syncthreads();   // Bs0 + Cs ready (vmcnt drained)

  f32x4 acc[4][4];
#pragma unroll
  for (int f = 0; f < 4; ++f)
#pragma unroll
    for (int g = 0; g < 4; ++g) acc[f][g] = (f32x4){0.f, 0.f, 0.f, 0.f};

  for (int it = 0; it < 32; ++it) {
    const int s0 = it * 2;
    // ---- even half: prefetch A(s0+1)->regs, stage B(s0+1)->Bs1, compute buf0
    LOAD_A(aNxt, s0 + 1);
    STAGE_B(s0 + 1, Bs1);
    COMPUTE(aCur, Bs0);
    __syncthreads();

    // ---- odd half: prefetch A(s0+2)->aCur, stage B(s0+2)->Bs0, compute buf1
    if (it < 31) {
      LOAD_A(aCur, s0 + 2);
      STAGE_B(s0 + 2, Bs0);
    }
    COMPUTE(aNxt, Bs1);

    if ((it & 3) == 3) {  // sub boundary (step s0+1 = 8*sub+7): per-lane top-2
      const int sub = (s0 + 1) >> 3;
      const int cbase = sub * 128 + wn * 64 + laneM;
      float Cg[4];
#pragma unroll
      for (int g = 0; g < 4; ++g) Cg[g] = Cs[cbase + g * 16];
#pragma unroll
      for (int f = 0; f < 4; ++f) {
#pragma unroll
        for (int r = 0; r < 4; ++r) {
          const int sl = f * 4 + r;
          const float Ar = Areg[f][r];
#pragma unroll
          for (int g = 0; g < 4; ++g) {
            float p2 = __fmul_rn(acc[f][g][r], 0x1p-15f);   // 2*dot, exact pow2
            float t1 = __fsub_rn(Ar, p2);
            float t  = __fadd_rn(t1, Cg[g]);
            u32 tb = __float_as_uint(t);          // t>0 -> bit cmp == float cmp
            u32 code = codeSub + (u32)(g * 16);
            bool lt1 = tb < v1b[sl];
            bool lt2 = tb < v2b[sl];
            v2b[sl] = lt1 ? v1b[sl] : (lt2 ? tb : v2b[sl]);
            c1v[sl] = lt1 ? code : c1v[sl];
            v1b[sl] = lt1 ? tb : v1b[sl];
          }
        }
      }
      codeSub += 128;
      // re-zero accumulators for the next sub
#pragma unroll
      for (int f = 0; f < 4; ++f)
#pragma unroll
        for (int g = 0; g < 4; ++g) acc[f][g] = (f32x4){0.f, 0.f, 0.f, 0.f};
    }
    __syncthreads();
  }

#undef LOAD_A
#undef STAGE_B
#undef COMPUTE

  // final cross-lane (laneM) top-2 reduce, once per kernel
#pragma unroll
  for (int sl = 0; sl < 16; ++sl) {
#pragma unroll
    for (int d = 1; d < 16; d <<= 1) {
      u32 o1 = (u32)__shfl_xor((int)v1b[sl], d);
      u32 oc = (u32)__shfl_xor((int)c1v[sl], d);
      u32 o2 = (u32)__shfl_xor((int)v2b[sl], d);
      u64 k  = ((u64)v1b[sl] << 32) | c1v[sl];
      u64 ko = ((u64)o1 << 32) | oc;
      u32 loser = v1b[sl] < o1 ? o1 : v1b[sl];
      u32 nv2 = min(loser, min(v2b[sl], o2));
      u64 nk = umin64(k, ko);
      v1b[sl] = (u32)(nk >> 32); c1v[sl] = (u32)nk; v2b[sl] = nv2;
    }
  }
  if (laneM == 0) {
#pragma unroll
    for (int f = 0; f < 4; ++f)
#pragma unroll
      for (int r = 0; r < 4; ++r) {
        const int tloc = wm * 64 + f * 16 + laneK * 4 + r;
        const int sl = f * 4 + r;
        t2k[tloc][wn] = ((u64)v1b[sl] << 32) | c1v[sl];
        t2v[tloc][wn] = v2b[sl];
      }
  }
  __syncthreads();
  if (tid < 128) {
    u64 k0 = t2k[tid][0], k1 = t2k[tid][1];
    u32 va = t2v[tid][0], vb = t2v[tid][1];
    u64 K1 = umin64(k0, k1);
    u32 loser = (u32)(umax64(k0, k1) >> 32);
    u32 V2 = min(min(va, vb), loser);
    const int token = ttile * 128 + tid;
    pk1[(size_t)token * 8 + cg] = K1;
    pv2[(size_t)token * 8 + cg] = __uint_as_float(V2);
  }
}

// ---- detect: merge 8 cgroup top-2, write candidate ids, flag near-ties ----
__global__ __launch_bounds__(256)
void vq_detect(const u64* __restrict__ pk1, const float* __restrict__ pv2,
               int* __restrict__ ids, int* __restrict__ rcnt, int* __restrict__ rlist) {
  const int token = blockIdx.x * 256 + threadIdx.x;
  u64 K1 = pk1[(size_t)token * 8];
  float V2 = pv2[(size_t)token * 8];
#pragma unroll
  for (int c = 1; c < 8; ++c) {
    u64 k1 = pk1[(size_t)token * 8 + c];
    float v2 = pv2[(size_t)token * 8 + c];
    u64 n1 = (k1 < K1) ? k1 : K1;
    u64 hi = (k1 < K1) ? K1 : k1;
    float loser = __uint_as_float((unsigned)(hi >> 32));
    V2 = fminf(fminf(V2, v2), loser);
    K1 = n1;
  }
  ids[token] = (int)(K1 & 0xffffffffull);
  float d1 = __uint_as_float((unsigned)(K1 >> 32));
  if (V2 - d1 < RESCUE_TAU) {
    int p = atomicAdd(rcnt, 1);
    rlist[p] = token;
  }
}

// ---- rescue: exact R3-chain rescan of flagged tokens over all codes ------
__global__ __launch_bounds__(256)
void vq_rescue(const float* __restrict__ z, const float* __restrict__ cb,
               const float* __restrict__ An, const float* __restrict__ Cn,
               const int* __restrict__ rcnt, const int* __restrict__ rlist,
               int* __restrict__ ids) {
  __shared__ float zrow[RPASS][256];
  __shared__ u64 red[256];
  const int tid = threadIdx.x;
  const int total = *rcnt;
  for (int base = blockIdx.x * RPASS; base < total; base += gridDim.x * RPASS) {
    const int np = min(RPASS, total - base);
    __syncthreads();
    for (int li = tid; li < np * 256; li += 256)
      zrow[li >> 8][li & 255] = z[(size_t)rlist[base + (li >> 8)] * DIM + (li & 255)];
    __syncthreads();
    float Atok[RPASS];
#pragma unroll
    for (int s = 0; s < RPASS; ++s) Atok[s] = (s < np) ? An[rlist[base + s]] : 0.f;
    u64 bkey[RPASS];
#pragma unroll
    for (int s = 0; s < RPASS; ++s) bkey[s] = ~0ull;
    for (int jj = 0; jj < KCB / 256; ++jj) {
      const int j = jj * 256 + tid;
      const float4* crow = reinterpret_cast<const float4*>(cb + (size_t)j * DIM);
      float dots[RPASS];
#pragma unroll
      for (int s = 0; s < RPASS; ++s) dots[s] = 0.f;
      for (int k4 = 0; k4 < 64; ++k4) {
        const float4 c4 = crow[k4];
#pragma unroll
        for (int s = 0; s < RPASS; ++s) {   // k ascending, same fmaf chain as R3
          const float4 z4 = *reinterpret_cast<const float4*>(&zrow[s][k4 * 4]);
          dots[s] = fmaf(z4.x, c4.x, dots[s]);
          dots[s] = fmaf(z4.y, c4.y, dots[s]);
          dots[s] = fmaf(z4.z, c4.z, dots[s]);
          dots[s] = fmaf(z4.w, c4.w, dots[s]);
        }
      }
      const float Cj = Cn[j];
#pragma unroll
      for (int s = 0; s < RPASS; ++s) {
        float p2 = __fmul_rn(2.0f, dots[s]);
        float t1 = __fsub_rn(Atok[s], p2);
        float t  = __fadd_rn(t1, Cj);
        u64 key = ((u64)__float_as_uint(t) << 32) | (u64)j;
        if (key < bkey[s]) bkey[s] = key;
      }
    }
    for (int s = 0; s < np; ++s) {
      __syncthreads();
      red[tid] = bkey[s];
      __syncthreads();
      for (int off = 128; off > 0; off >>= 1) {
        if (tid < off) { u64 o = red[tid + off]; if (o < red[tid]) red[tid] = o; }
        __syncthreads();
      }
      if (tid == 0) ids[rlist[base + s]] = (int)(red[0] & 0xffffffffull);
    }
  }
}

// ---- finalize: gather z_q, ids; block-reduced loss partials (no atomics) --
__global__ __launch_bounds__(256)
void vq_finalize_ids(const float* __restrict__ z, const float* __restrict__ cb,
                     const int* __restrict__ ids, float* __restrict__ out,
                     double* __restrict__ part) {
  __shared__ double sred[4];
  const int g64 = threadIdx.x >> 6, lane = threadIdx.x & 63;
  double s = 0.0;
#pragma unroll
  for (int i = 0; i < 4; ++i) {
    const int n = blockIdx.x * 16 + i * 4 + g64;
    const int bk = ids[n];
    const float4 c4 = *reinterpret_cast<const float4*>(&cb[(size_t)bk * DIM + lane * 4]);
    const float4 z4 = *reinterpret_cast<const float4*>(&z[(size_t)n * DIM + lane * 4]);
    *reinterpret_cast<float4*>(&out[(size_t)n * DIM + lane * 4]) = c4;
    float dx = __fsub_rn(c4.x, z4.x), dy = __fsub_rn(c4.y, z4.y);
    float dz = __fsub_rn(c4.z, z4.z), dw = __fsub_rn(c4.w, z4.w);
    s += (double)dx * dx + (double)dy * dy + (double)dz * dz + (double)dw * dw;
    if (lane == 0) out[(size_t)NTOK * DIM + n] = (float)bk;
  }
#pragma unroll
  for (int off = 32; off > 0; off >>= 1) s += __shfl_down(s, off);
  if (lane == 0) sred[g64] = s;
  __syncthreads();
  if (threadIdx.x == 0)
    part[blockIdx.x] = (sred[0] + sred[1]) + (sred[2] + sred[3]);
}

__global__ __launch_bounds__(256)
void vq_loss_write(const double* __restrict__ part, float* __restrict__ out) {
  __shared__ double red[256];
  double s = 0.0;
  for (int i = threadIdx.x; i < 2048; i += 256) s += part[i];
  red[threadIdx.x] = s;
  __syncthreads();
  for (int off = 128; off > 0; off >>= 1) {
    if (threadIdx.x < off) red[threadIdx.x] += red[threadIdx.x + off];
    __syncthreads();
  }
  if (threadIdx.x == 0)
    out[(size_t)NTOK * DIM + NTOK] =
        (float)(0.25 * red[0] / (double)((size_t)NTOK * DIM));
}

// ======================= R3 fallback path (ws too small) ==================
#define NCHUNK 8
#define CHUNK 1024
#define TT 128
#define CT 128
#define DC 32

__global__ __launch_bounds__(256)
void vq_argmin_kernel(const float* __restrict__ z, const float* __restrict__ cb,
                      const float* __restrict__ An, const float* __restrict__ Cn,
                      float* __restrict__ pv, int* __restrict__ pk) {
  __shared__ float zs[DC * TT];
  __shared__ float cs[DC * CT];
  const int tid = threadIdx.x;
  const int tx = tid & 15, ty = tid >> 4;
  const int chunk = blockIdx.x & 7;
  const int tile = blockIdx.x >> 3;
  const int base_t = tile * TT;
  const int base_k = chunk * CHUNK;
  float Areg[8];
#pragma unroll
  for (int i = 0; i < 8; ++i) Areg[i] = An[base_t + ty * 8 + i];
  float bestv[8]; int bestk[8];
#pragma unroll
  for (int i = 0; i < 8; ++i) { bestv[i] = INFINITY; bestk[i] = 0; }
  for (int st = 0; st < CHUNK / CT; ++st) {
    const int kb0 = base_k + st * CT;
    float acc[8][8];
#pragma unroll
    for (int i = 0; i < 8; ++i)
#pragma unroll
      for (int j = 0; j < 8; ++j) acc[i][j] = 0.f;
    for (int dc = 0; dc < DIM / DC; ++dc) {
      __syncthreads();
#pragma unroll
      for (int li = tid; li < DC * TT / 4; li += 256) {
        const int row = li >> 3;
        const int dv = li & 7;
        const int ibase = dv * 4 * 128 + (row ^ (dv << 2) ^ ((row & 32) >> 3));
        float4 v = *reinterpret_cast<const float4*>(
            &z[(size_t)(base_t + row) * DIM + dc * DC + dv * 4]);
        zs[ibase] = v.x; zs[ibase + 128] = v.y;
        zs[ibase + 256] = v.z; zs[ibase + 384] = v.w;
        float4 c = *reinterpret_cast<const float4*>(
            &cb[(size_t)(kb0 + row) * DIM + dc * DC + dv * 4]);
        cs[ibase] = c.x; cs[ibase + 128] = c.y;
        cs[ibase + 256] = c.z; cs[ibase + 384] = c.w;
      }
      __syncthreads();
#pragma unroll
      for (int dd = 0; dd < DC / 4; ++dd) {
        const int s1 = dd << 2;
        const float* zp0 = &zs[dd * 4 * 128 + ((ty * 8) ^ s1 ^ (ty & 4))];
        const float* zp1 = &zs[dd * 4 * 128 + ((ty * 8 + 4) ^ s1 ^ (ty & 4))];
        const float* cp0 = &cs[dd * 4 * 128 + ((tx * 8) ^ s1 ^ (tx & 4))];
        const float* cp1 = &cs[dd * 4 * 128 + ((tx * 8 + 4) ^ s1 ^ (tx & 4))];
#pragma unroll
        for (int q = 0; q < 4; ++q) {
          const float4 za  = *reinterpret_cast<const float4*>(zp0 + q * 128);
          const float4 zb  = *reinterpret_cast<const float4*>(zp1 + q * 128);
          const float4 ca  = *reinterpret_cast<const float4*>(cp0 + q * 128);
          const float4 cbv = *reinterpret_cast<const float4*>(cp1 + q * 128);
          const float zv[8] = {za.x, za.y, za.z, za.w, zb.x, zb.y, zb.z, zb.w};
          const float cv[8] = {ca.x, ca.y, ca.z, ca.w, cbv.x, cbv.y, cbv.z, cbv.w};
#pragma unroll
          for (int i = 0; i < 8; ++i)
#pragma unroll
            for (int j = 0; j < 8; ++j)
              acc[i][j] = fmaf(zv[i], cv[j], acc[i][j]);
        }
      }
    }
#pragma unroll
    for (int j = 0; j < 8; ++j) {
      const int klocal = st * CT + tx * 8 + j;
      const float Ck = Cn[base_k + klocal];
#pragma unroll
      for (int i = 0; i < 8; ++i) {
        float p2 = __fmul_rn(2.0f, acc[i][j]);
        float t1 = __fsub_rn(Areg[i], p2);
        float t  = __fadd_rn(t1, Ck);
        if (t < bestv[i]) { bestv[i] = t; bestk[i] = klocal; }
      }
    }
  }
  __syncthreads();
  float (*mv)[16] = reinterpret_cast<float(*)[16]>(zs);
  int   (*mk)[16] = reinterpret_cast<int(*)[16]>(zs + TT * 16);
#pragma unroll
  for (int i = 0; i < 8; ++i) { mv[ty * 8 + i][tx] = bestv[i]; mk[ty * 8 + i][tx] = bestk[i]; }
  __syncthreads();
  if (tid < TT) {
    float bv = mv[tid][0]; int bk = mk[tid][0];
#pragma unroll
    for (int x = 1; x < 16; ++x) {
      float v = mv[tid][x]; int k = mk[tid][x];
      if (v < bv || (v == bv && k < bk)) { bv = v; bk = k; }
    }
    size_t idx = (size_t)(base_t + tid) * NCHUNK + chunk;
    pv[idx] = bv;
    pk[idx] = base_k + bk;
  }
}

__global__ __launch_bounds__(256)
void vq_finalize(const float* __restrict__ z, const float* __restrict__ cb,
                 const float* __restrict__ pv, const int* __restrict__ pk,
                 float* __restrict__ out, double* __restrict__ loss_acc) {
  const int n = blockIdx.x * 4 + (threadIdx.x >> 6);
  const int lane = threadIdx.x & 63;
  float bv = INFINITY; int bk = 0;
#pragma unroll
  for (int c = 0; c < NCHUNK; ++c) {
    float v = pv[(size_t)n * NCHUNK + c];
    int k = pk[(size_t)n * NCHUNK + c];
    if (v < bv || (v == bv && k < bk)) { bv = v; bk = k; }
  }
  const float4 c4 = *reinterpret_cast<const float4*>(&cb[(size_t)bk * DIM + lane * 4]);
  const float4 z4 = *reinterpret_cast<const float4*>(&z[(size_t)n * DIM + lane * 4]);
  *reinterpret_cast<float4*>(&out[(size_t)n * DIM + lane * 4]) = c4;
  float dx = __fsub_rn(c4.x, z4.x), dy = __fsub_rn(c4.y, z4.y);
  float dz = __fsub_rn(c4.z, z4.z), dw = __fsub_rn(c4.w, z4.w);
  double s = (double)dx * dx + (double)dy * dy + (double)dz * dz + (double)dw * dw;
#pragma unroll
  for (int off = 32; off > 0; off >>= 1) s += __shfl_down(s, off);
  if (lane == 0) {
    out[(size_t)NTOK * DIM + n] = (float)bk;
    atomicAdd(loss_acc, s);
  }
}

__global__ void vq_loss_write_fb(const double* __restrict__ loss_acc, float* __restrict__ out) {
  out[(size_t)NTOK * DIM + NTOK] = (float)(0.25 * (*loss_acc) / (double)((size_t)NTOK * DIM));
}

// ==========================================================================
extern "C" void kernel_launch(void* const* d_in, const int* in_sizes, int n_in,
                              void* d_out, int out_size, void* d_ws, size_t ws_size,
                              hipStream_t stream) {
  const float* z  = (const float*)d_in[0];
  const float* cb = (const float*)d_in[1];
  float* out = (float*)d_out;
  char* ws = (char*)d_ws;

  if (ws_size >= WS_NEED) {
    float*     An   = (float*)(ws + OFF_AN);
    float*     Cn   = (float*)(ws + OFF_CN);
    int*       ids  = (int*)(ws + OFF_IDS);
    int*       rcnt = (int*)(ws + OFF_RCNT);
    int*       rlist= (int*)(ws + OFF_RLIST);
    double*    part = (double*)(ws + OFF_PART);
    u64*       pk1  = (u64*)(ws + OFF_PK1);
    float*     pv2  = (float*)(ws + OFF_PV2);
    _Float16*  z16  = (_Float16*)(ws + OFF_Z16);
    _Float16*  c16  = (_Float16*)(ws + OFF_CB16);

    hipMemsetAsync(rcnt, 0, 128, stream);
    rownorm256_np<<<NTOK / 256, 256, 0, stream>>>(z, An, NTOK);
    rownorm256_np<<<KCB / 256, 256, 0, stream>>>(cb, Cn, KCB);
    conv_z16<<<256 * 8, 128, 0, stream>>>(z, z16);
    conv_cb16<<<32 * 8, 256, 0, stream>>>(cb, c16);
    vq_mfma_top2<<<2048, 256, 0, stream>>>(z16, c16, An, Cn, pk1, pv2);
    vq_detect<<<NTOK / 256, 256, 0, stream>>>(pk1, pv2, ids, rcnt, rlist);
    vq_rescue<<<1024, 256, 0, stream>>>(z, cb, An, Cn, rcnt, rlist, ids);
    vq_finalize_ids<<<NTOK / 16, 256, 0, stream>>>(z, cb, ids, out, part);
    vq_loss_write<<<1, 256, 0, stream>>>(part, out);
  } else {
    // R3 fallback (needs ~2.26 MB)
    float*  An = (float*)(ws);
    float*  Cn = (float*)(ws + 131072);
    float*  pv = (float*)(ws + 163840);
    int*    pk = (int*)(ws + 1212416);
    double* loss = (double*)(ws + 2260992);
    hipMemsetAsync(loss, 0, sizeof(double), stream);
    rownorm256_np<<<NTOK / 256, 256, 0, stream>>>(z, An, NTOK);
    rownorm256_np<<<KCB / 256, 256, 0, stream>>>(cb, Cn, KCB);
    vq_argmin_kernel<<<(NTOK / TT) * NCHUNK, 256, 0, stream>>>(z, cb, An, Cn, pv, pk);
    vq_finalize<<<NTOK / 4, 256, 0, stream>>>(z, cb, pv, pk, out, loss);
    vq_loss_write_fb<<<1, 1, 0, stream>>>(loss, out);
  }
}